// Round 1
// baseline (808.040 us; speedup 1.0000x reference)
//
#include <hip/hip_runtime.h>
#include <math.h>

#define N_ENT 50000
#define N_USR 10000
#define NN    60000
#define DD    64
#define H0    128
#define ENCD  32
#define RR    16

__device__ __forceinline__ float4 ld4(const float* p){ return *reinterpret_cast<const float4*>(p); }
__device__ __forceinline__ void st4(float* p, float4 v){ *reinterpret_cast<float4*>(p) = v; }

// w_sum[layer][r*64+j] = sum_k Wr[r][j][k]
__global__ __launch_bounds__(256) void k_wsum(const float* __restrict__ Wr1, const float* __restrict__ Wr2,
                                              float* __restrict__ wsum){
  int i = blockIdx.x*256 + threadIdx.x;        // 0..2047
  if (i >= 2*RR*DD) return;
  const float* Wr = (i < RR*DD) ? Wr1 : Wr2;
  int loc = i & (RR*DD - 1);                   // r*64+j
  const float* p = Wr + (size_t)loc*32;
  float s = 0.f;
  #pragma unroll
  for (int k=0;k<32;k++) s += p[k];
  wsum[i] = s;
}

// h1 = relu(emb @ W0 + b0), stored tiled: h1t[tile][n][16]
__global__ __launch_bounds__(256) void k_enc1(const float* __restrict__ ent, const float* __restrict__ usr,
    const float* __restrict__ W0, const float* __restrict__ b0, float* __restrict__ h1t){
  int n = blockIdx.x*256 + threadIdx.x;
  if (n >= NN) return;
  int j0 = blockIdx.y * 16;
  const float* xr = (n < N_ENT) ? (ent + (size_t)n*DD) : (usr + (size_t)(n-N_ENT)*DD);
  float xv[DD];
  #pragma unroll
  for (int q=0;q<DD/4;q++){ float4 v = ld4(xr + 4*q); xv[4*q]=v.x; xv[4*q+1]=v.y; xv[4*q+2]=v.z; xv[4*q+3]=v.w; }
  float acc[16];
  #pragma unroll
  for (int t=0;t<16;t++) acc[t] = b0[j0+t];
  const float* w = W0 + j0;
  #pragma unroll
  for (int d=0; d<DD; d++){
    #pragma unroll
    for (int t=0;t<16;t++) acc[t] = fmaf(xv[d], w[(size_t)d*H0 + t], acc[t]);
  }
  float* out = h1t + ((size_t)blockIdx.y * NN + n) * 16;
  #pragma unroll
  for (int q=0;q<4;q++){
    float4 v; v.x=fmaxf(acc[4*q],0.f); v.y=fmaxf(acc[4*q+1],0.f); v.z=fmaxf(acc[4*q+2],0.f); v.w=fmaxf(acc[4*q+3],0.f);
    st4(out + 4*q, v);
  }
}

// enc = h1 @ W1 + b1   (no activation), enc row-major [NN][32]
__global__ __launch_bounds__(256) void k_enc2(const float* __restrict__ h1t, const float* __restrict__ W1,
    const float* __restrict__ b1, float* __restrict__ enc){
  int n = blockIdx.x*256 + threadIdx.x;
  if (n >= NN) return;
  int k0 = blockIdx.y * 16;
  float acc[16];
  #pragma unroll
  for (int t=0;t<16;t++) acc[t] = b1[k0+t];
  for (int tj=0; tj<8; tj++){
    const float* hr = h1t + ((size_t)tj * NN + n) * 16;
    float h[16];
    #pragma unroll
    for (int q=0;q<4;q++){ float4 v = ld4(hr+4*q); h[4*q]=v.x; h[4*q+1]=v.y; h[4*q+2]=v.z; h[4*q+3]=v.w; }
    const float* w = W1 + (size_t)tj*16*ENCD + k0;
    #pragma unroll
    for (int jj=0;jj<16;jj++){
      #pragma unroll
      for (int t=0;t<16;t++) acc[t] = fmaf(h[jj], w[(size_t)jj*ENCD + t], acc[t]);
    }
  }
  float* out = enc + (size_t)n*ENCD + k0;
  #pragma unroll
  for (int q=0;q<4;q++){ float4 v; v.x=acc[4*q]; v.y=acc[4*q+1]; v.z=acc[4*q+2]; v.w=acc[4*q+3]; st4(out+4*q, v); }
}

// h2 = relu(enc @ dW0 + db0), tiled h2t[tile][n][16]
__global__ __launch_bounds__(256) void k_dec1(const float* __restrict__ enc, const float* __restrict__ dW0,
    const float* __restrict__ db0, float* __restrict__ h2t){
  int n = blockIdx.x*256 + threadIdx.x;
  if (n >= NN) return;
  int j0 = blockIdx.y * 16;
  const float* xr = enc + (size_t)n*ENCD;
  float xv[ENCD];
  #pragma unroll
  for (int q=0;q<ENCD/4;q++){ float4 v = ld4(xr + 4*q); xv[4*q]=v.x; xv[4*q+1]=v.y; xv[4*q+2]=v.z; xv[4*q+3]=v.w; }
  float acc[16];
  #pragma unroll
  for (int t=0;t<16;t++) acc[t] = db0[j0+t];
  const float* w = dW0 + j0;
  #pragma unroll
  for (int d=0; d<ENCD; d++){
    #pragma unroll
    for (int t=0;t<16;t++) acc[t] = fmaf(xv[d], w[(size_t)d*H0 + t], acc[t]);
  }
  float* out = h2t + ((size_t)blockIdx.y * NN + n) * 16;
  #pragma unroll
  for (int q=0;q<4;q++){
    float4 v; v.x=fmaxf(acc[4*q],0.f); v.y=fmaxf(acc[4*q+1],0.f); v.z=fmaxf(acc[4*q+2],0.f); v.w=fmaxf(acc[4*q+3],0.f);
    st4(out + 4*q, v);
  }
}

// dec = h2 @ dW1 + db1 ; loss += sum((dec - emb)^2) / (NN*DD)
__global__ __launch_bounds__(256) void k_dec2(const float* __restrict__ h2t, const float* __restrict__ dW1,
    const float* __restrict__ db1, const float* __restrict__ ent, const float* __restrict__ usr,
    float* __restrict__ loss_out){
  int n = blockIdx.x*256 + threadIdx.x;
  int k0 = blockIdx.y * 16;
  float part = 0.f;
  if (n < NN){
    float acc[16];
    #pragma unroll
    for (int t=0;t<16;t++) acc[t] = db1[k0+t];
    for (int tj=0; tj<8; tj++){
      const float* hr = h2t + ((size_t)tj * NN + n) * 16;
      float h[16];
      #pragma unroll
      for (int q=0;q<4;q++){ float4 v = ld4(hr+4*q); h[4*q]=v.x; h[4*q+1]=v.y; h[4*q+2]=v.z; h[4*q+3]=v.w; }
      const float* w = dW1 + (size_t)tj*16*DD + k0;
      #pragma unroll
      for (int jj=0;jj<16;jj++){
        #pragma unroll
        for (int t=0;t<16;t++) acc[t] = fmaf(h[jj], w[(size_t)jj*DD + t], acc[t]);
      }
    }
    const float* xr = (n < N_ENT) ? (ent + (size_t)n*DD + k0) : (usr + (size_t)(n-N_ENT)*DD + k0);
    #pragma unroll
    for (int t=0;t<16;t++){ float d_ = acc[t] - xr[t]; part = fmaf(d_, d_, part); }
  }
  #pragma unroll
  for (int off=32; off>0; off>>=1) part += __shfl_down(part, off, 64);
  __shared__ float sred[4];
  if ((threadIdx.x & 63)==0) sred[threadIdx.x>>6] = part;
  __syncthreads();
  if (threadIdx.x==0){
    float s = (sred[0]+sred[1]+sred[2]+sred[3]) * (1.0f/((float)NN*(float)DD));
    atomicAdd(loss_out, s);
  }
}

__global__ __launch_bounds__(256) void k_hist(const int* __restrict__ edst, int* __restrict__ cnt, int E_){
  int e = blockIdx.x*256 + threadIdx.x;
  if (e >= E_) return;
  atomicAdd(&cnt[edst[e]], 1);
}

__global__ __launch_bounds__(256) void k_bsum(const int* __restrict__ cnt, int* __restrict__ bsum){
  int i = blockIdx.x*256 + threadIdx.x;
  int v = (i < NN) ? cnt[i] : 0;
  #pragma unroll
  for (int off=32; off>0; off>>=1) v += __shfl_down(v, off, 64);
  __shared__ int s[4];
  if ((threadIdx.x & 63)==0) s[threadIdx.x>>6] = v;
  __syncthreads();
  if (threadIdx.x==0) bsum[blockIdx.x] = s[0]+s[1]+s[2]+s[3];
}

__global__ __launch_bounds__(256) void k_scanb(int* __restrict__ bsum, int nb){
  __shared__ int s[256];
  int t = threadIdx.x;
  int v = (t < nb) ? bsum[t] : 0;
  s[t] = v;
  __syncthreads();
  #pragma unroll
  for (int off=1; off<256; off<<=1){
    int a = (t>=off) ? s[t-off] : 0;
    __syncthreads();
    s[t] += a;
    __syncthreads();
  }
  if (t < nb) bsum[t] = s[t] - v;   // exclusive block offsets
}

__global__ __launch_bounds__(256) void k_scanc(const int* __restrict__ cnt, const int* __restrict__ bsum,
                                               int* __restrict__ rowp){
  __shared__ int s[256];
  int t = threadIdx.x;
  int i = blockIdx.x*256 + t;
  int v = (i < NN) ? cnt[i] : 0;
  s[t] = v;
  __syncthreads();
  #pragma unroll
  for (int off=1; off<256; off<<=1){
    int a = (t>=off) ? s[t-off] : 0;
    __syncthreads();
    s[t] += a;
    __syncthreads();
  }
  if (i < NN) rowp[i+1] = bsum[blockIdx.x] + s[t];
  if (i == 0) rowp[0] = 0;
}

__global__ __launch_bounds__(256) void k_scatter(const int* __restrict__ esrc, const int* __restrict__ edst,
    const int* __restrict__ rowp, int* __restrict__ fill, int* __restrict__ src_s, int* __restrict__ pos, int E_){
  int e = blockIdx.x*256 + threadIdx.x;
  if (e >= E_) return;
  int d_ = edst[e];
  int p = rowp[d_] + atomicAdd(&fill[d_], 1);
  src_s[p] = esrc[e];
  pos[e] = p;
}

// gate = sigmoid(concat(x[dst],x[src]) . w_sum[rel]); write to sorted slot
__global__ __launch_bounds__(256) void k_gate(const float* __restrict__ x, const float* __restrict__ wsum,
    const int* __restrict__ esrc, const int* __restrict__ edst, const int* __restrict__ erel,
    const int* __restrict__ pos, float* __restrict__ gate_s, int E_){
  __shared__ float wl[RR*DD];                  // [j][rel]: wl[j*16+rel]
  for (int i = threadIdx.x; i < RR*DD; i += 256){
    int rel = i & 15; int j = i >> 4;
    wl[i] = wsum[rel*DD + j];
  }
  __syncthreads();
  int e = blockIdx.x*256 + threadIdx.x;
  if (e >= E_) return;
  int s = esrc[e], d_ = edst[e], r = erel[e];
  const float* xd = x + (size_t)d_*ENCD;
  const float* xs = x + (size_t)s*ENCD;
  float xdv[ENCD], xsv[ENCD];
  #pragma unroll
  for (int q=0;q<8;q++){ float4 v = ld4(xd+4*q); xdv[4*q]=v.x; xdv[4*q+1]=v.y; xdv[4*q+2]=v.z; xdv[4*q+3]=v.w; }
  #pragma unroll
  for (int q=0;q<8;q++){ float4 v = ld4(xs+4*q); xsv[4*q]=v.x; xsv[4*q+1]=v.y; xsv[4*q+2]=v.z; xsv[4*q+3]=v.w; }
  float z = 0.f;
  #pragma unroll
  for (int j=0;j<32;j++) z = fmaf(xdv[j], wl[j*16 + r], z);
  #pragma unroll
  for (int j=0;j<32;j++) z = fmaf(xsv[j], wl[(32+j)*16 + r], z);
  float g = 1.f/(1.f + expf(-z));
  gate_s[pos[e]] = g;
}

// scatter-mean via CSR gather: 32 lanes per node
__global__ __launch_bounds__(256) void k_agg(const float* __restrict__ x, const int* __restrict__ src_s,
    const float* __restrict__ gate_s, const int* __restrict__ rowp, float* __restrict__ agg){
  int node = blockIdx.x*8 + (threadIdx.x >> 5);
  int f = threadIdx.x & 31;
  if (node >= NN) return;
  int beg = rowp[node], end = rowp[node+1];
  float acc = 0.f;
  for (int i=beg; i<end; i++){
    int s = src_s[i];
    float g = gate_s[i];
    acc = fmaf(x[(size_t)s*ENCD + f], g, acc);
  }
  int deg = end - beg;
  agg[(size_t)node*ENCD + f] = (deg > 0) ? (acc / (float)deg) : 0.f;
}

// out = leaky_relu(concat(x,agg) @ W + b), W is [64][outd]
__global__ __launch_bounds__(256) void k_lin(const float* __restrict__ x, const float* __restrict__ agg,
    const float* __restrict__ W, const float* __restrict__ b, float* __restrict__ out, int outd){
  int n = blockIdx.x*256 + threadIdx.x;
  if (n >= NN) return;
  int k0 = blockIdx.y * 16;
  const float* xr = x   + (size_t)n*ENCD;
  const float* ar = agg + (size_t)n*ENCD;
  float xv[32], av[32];
  #pragma unroll
  for (int q=0;q<8;q++){ float4 v = ld4(xr+4*q); xv[4*q]=v.x; xv[4*q+1]=v.y; xv[4*q+2]=v.z; xv[4*q+3]=v.w; }
  #pragma unroll
  for (int q=0;q<8;q++){ float4 v = ld4(ar+4*q); av[4*q]=v.x; av[4*q+1]=v.y; av[4*q+2]=v.z; av[4*q+3]=v.w; }
  float acc[16];
  #pragma unroll
  for (int t=0;t<16;t++) acc[t] = b[k0+t];
  #pragma unroll
  for (int j=0;j<32;j++){
    #pragma unroll
    for (int t=0;t<16;t++) acc[t] = fmaf(xv[j], W[(size_t)j*outd + k0 + t], acc[t]);
  }
  #pragma unroll
  for (int j=0;j<32;j++){
    #pragma unroll
    for (int t=0;t<16;t++) acc[t] = fmaf(av[j], W[(size_t)(32+j)*outd + k0 + t], acc[t]);
  }
  float* o = out + (size_t)n*outd + k0;
  #pragma unroll
  for (int q=0;q<4;q++){
    float4 v;
    float a0=acc[4*q],a1=acc[4*q+1],a2=acc[4*q+2],a3=acc[4*q+3];
    v.x = a0>0.f? a0 : 0.01f*a0;
    v.y = a1>0.f? a1 : 0.01f*a1;
    v.z = a2>0.f? a2 : 0.01f*a2;
    v.w = a3>0.f? a3 : 0.01f*a3;
    st4(o + 4*q, v);
  }
}

__global__ __launch_bounds__(256) void k_score(const float* __restrict__ x1, const float* __restrict__ x2,
    const int* __restrict__ users, const int* __restrict__ items, float* __restrict__ out, int Bn){
  int b = blockIdx.x*256 + threadIdx.x;
  if (b >= Bn) return;
  int u  = N_ENT + users[b];
  int it = items[b];
  const float* a1 = x1 + (size_t)u*32;
  const float* c1 = x1 + (size_t)it*32;
  const float* a2 = x2 + (size_t)u*16;
  const float* c2 = x2 + (size_t)it*16;
  float s = 0.f;
  #pragma unroll
  for (int q=0;q<8;q++){
    float4 va=ld4(a1+4*q), vb=ld4(c1+4*q);
    s = fmaf(va.x,vb.x,s); s = fmaf(va.y,vb.y,s); s = fmaf(va.z,vb.z,s); s = fmaf(va.w,vb.w,s);
  }
  #pragma unroll
  for (int q=0;q<4;q++){
    float4 va=ld4(a2+4*q), vb=ld4(c2+4*q);
    s = fmaf(va.x,vb.x,s); s = fmaf(va.y,vb.y,s); s = fmaf(va.z,vb.z,s); s = fmaf(va.w,vb.w,s);
  }
  out[b] = s;
}

extern "C" void kernel_launch(void* const* d_in, const int* in_sizes, int n_in,
                              void* d_out, int out_size, void* d_ws, size_t ws_size,
                              hipStream_t stream){
  const int*   users   = (const int*)d_in[0];
  const int*   items   = (const int*)d_in[1];
  const int*   esrc    = (const int*)d_in[2];
  const int*   edst    = (const int*)d_in[3];
  const int*   erel    = (const int*)d_in[4];
  const float* ent     = (const float*)d_in[5];
  const float* usr     = (const float*)d_in[6];
  const float* enc_W0  = (const float*)d_in[7];
  const float* enc_b0  = (const float*)d_in[8];
  const float* enc_W1  = (const float*)d_in[9];
  const float* enc_b1  = (const float*)d_in[10];
  const float* dec_W0  = (const float*)d_in[11];
  const float* dec_b0  = (const float*)d_in[12];
  const float* dec_W1  = (const float*)d_in[13];
  const float* dec_b1  = (const float*)d_in[14];
  const float* Wr1     = (const float*)d_in[15];
  const float* lin_W1  = (const float*)d_in[16];
  const float* lin_b1  = (const float*)d_in[17];
  const float* Wr2     = (const float*)d_in[18];
  const float* lin_W2  = (const float*)d_in[19];
  const float* lin_b2  = (const float*)d_in[20];
  const int E = in_sizes[2];
  const int B = in_sizes[0];

  char* wp = (char*)d_ws;
  auto carve = [&](size_t bytes)->char*{ char* p = wp; wp += (bytes + 255) & ~(size_t)255; return p; };
  float* enc    = (float*)carve((size_t)NN*32*4);
  float* x1     = (float*)carve((size_t)NN*32*4);
  float* x2     = (float*)carve((size_t)NN*16*4);
  float* agg    = (float*)carve((size_t)NN*32*4);
  float* h1t    = (float*)carve((size_t)NN*128*4);   // reused for h2t
  float* wsum   = (float*)carve((size_t)2*RR*DD*4);
  float* gate_s = (float*)carve((size_t)E*4);
  int*   src_s  = (int*)  carve((size_t)E*4);
  int*   pos    = (int*)  carve((size_t)E*4);
  int*   cnt    = (int*)  carve((size_t)2*NN*4);     // cnt then fill, one memset
  int*   fill   = cnt + NN;
  int*   rowp   = (int*)  carve(((size_t)NN+1)*4);
  int*   bsum   = (int*)  carve(256*4);

  const int nbN = (NN + 255)/256;   // 235
  const int nbE = (E  + 255)/256;
  dim3 blk(256);

  hipMemsetAsync(d_out, 0, (size_t)out_size*sizeof(float), stream);
  hipMemsetAsync(cnt, 0, (size_t)2*NN*sizeof(int), stream);

  k_wsum <<<dim3((2*RR*DD+255)/256), blk, 0, stream>>>(Wr1, Wr2, wsum);
  k_enc1 <<<dim3(nbN, 8), blk, 0, stream>>>(ent, usr, enc_W0, enc_b0, h1t);
  k_enc2 <<<dim3(nbN, 2), blk, 0, stream>>>(h1t, enc_W1, enc_b1, enc);
  k_dec1 <<<dim3(nbN, 8), blk, 0, stream>>>(enc, dec_W0, dec_b0, h1t);
  k_dec2 <<<dim3(nbN, 4), blk, 0, stream>>>(h1t, dec_W1, dec_b1, ent, usr, ((float*)d_out) + B);

  k_hist   <<<nbE, blk, 0, stream>>>(edst, cnt, E);
  k_bsum   <<<nbN, blk, 0, stream>>>(cnt, bsum);
  k_scanb  <<<1,   blk, 0, stream>>>(bsum, nbN);
  k_scanc  <<<nbN, blk, 0, stream>>>(cnt, bsum, rowp);
  k_scatter<<<nbE, blk, 0, stream>>>(esrc, edst, rowp, fill, src_s, pos, E);

  k_gate <<<nbE, blk, 0, stream>>>(enc, wsum, esrc, edst, erel, pos, gate_s, E);
  k_agg  <<<(NN*32+255)/256, blk, 0, stream>>>(enc, src_s, gate_s, rowp, agg);
  k_lin  <<<dim3(nbN, 2), blk, 0, stream>>>(enc, agg, lin_W1, lin_b1, x1, 32);

  k_gate <<<nbE, blk, 0, stream>>>(x1, wsum + RR*DD, esrc, edst, erel, pos, gate_s, E);
  k_agg  <<<(NN*32+255)/256, blk, 0, stream>>>(x1, src_s, gate_s, rowp, agg);
  k_lin  <<<dim3(nbN, 1), blk, 0, stream>>>(x1, agg, lin_W2, lin_b2, x2, 16);

  k_score<<<(B+255)/256, blk, 0, stream>>>(x1, x2, users, items, (float*)d_out, B);
}

// Round 2
// 688.744 us; speedup vs baseline: 1.1732x; 1.1732x over previous
//
#include <hip/hip_runtime.h>
#include <math.h>

#define N_ENT 50000
#define N_USR 10000
#define NN    60000
#define DD    64
#define H0    128
#define ENCD  32
#define RR    16

__device__ __forceinline__ float4 ld4(const float* p){ return *reinterpret_cast<const float4*>(p); }
__device__ __forceinline__ void st4(float* p, float4 v){ *reinterpret_cast<float4*>(p) = v; }

// w_sum[layer][r*64+j] = sum_k Wr[r][j][k]
__global__ __launch_bounds__(256) void k_wsum(const float* __restrict__ Wr1, const float* __restrict__ Wr2,
                                              float* __restrict__ wsum){
  int i = blockIdx.x*256 + threadIdx.x;        // 0..2047
  if (i >= 2*RR*DD) return;
  const float* Wr = (i < RR*DD) ? Wr1 : Wr2;
  int loc = i & (RR*DD - 1);                   // r*64+j
  const float* p = Wr + (size_t)loc*32;
  float s = 0.f;
  #pragma unroll
  for (int k=0;k<32;k++) s += p[k];
  wsum[i] = s;
}

// h1 = relu(emb @ W0 + b0), stored tiled: h1t[tile][n][16]
__global__ __launch_bounds__(256) void k_enc1(const float* __restrict__ ent, const float* __restrict__ usr,
    const float* __restrict__ W0, const float* __restrict__ b0, float* __restrict__ h1t){
  int n = blockIdx.x*256 + threadIdx.x;
  if (n >= NN) return;
  int j0 = blockIdx.y * 16;
  const float* xr = (n < N_ENT) ? (ent + (size_t)n*DD) : (usr + (size_t)(n-N_ENT)*DD);
  float xv[DD];
  #pragma unroll
  for (int q=0;q<DD/4;q++){ float4 v = ld4(xr + 4*q); xv[4*q]=v.x; xv[4*q+1]=v.y; xv[4*q+2]=v.z; xv[4*q+3]=v.w; }
  float acc[16];
  #pragma unroll
  for (int t=0;t<16;t++) acc[t] = b0[j0+t];
  const float* w = W0 + j0;
  #pragma unroll
  for (int d=0; d<DD; d++){
    #pragma unroll
    for (int t=0;t<16;t++) acc[t] = fmaf(xv[d], w[(size_t)d*H0 + t], acc[t]);
  }
  float* out = h1t + ((size_t)blockIdx.y * NN + n) * 16;
  #pragma unroll
  for (int q=0;q<4;q++){
    float4 v; v.x=fmaxf(acc[4*q],0.f); v.y=fmaxf(acc[4*q+1],0.f); v.z=fmaxf(acc[4*q+2],0.f); v.w=fmaxf(acc[4*q+3],0.f);
    st4(out + 4*q, v);
  }
}

// enc = h1 @ W1 + b1   (no activation), enc row-major [NN][32]
__global__ __launch_bounds__(256) void k_enc2(const float* __restrict__ h1t, const float* __restrict__ W1,
    const float* __restrict__ b1, float* __restrict__ enc){
  int n = blockIdx.x*256 + threadIdx.x;
  if (n >= NN) return;
  int k0 = blockIdx.y * 16;
  float acc[16];
  #pragma unroll
  for (int t=0;t<16;t++) acc[t] = b1[k0+t];
  for (int tj=0; tj<8; tj++){
    const float* hr = h1t + ((size_t)tj * NN + n) * 16;
    float h[16];
    #pragma unroll
    for (int q=0;q<4;q++){ float4 v = ld4(hr+4*q); h[4*q]=v.x; h[4*q+1]=v.y; h[4*q+2]=v.z; h[4*q+3]=v.w; }
    const float* w = W1 + (size_t)tj*16*ENCD + k0;
    #pragma unroll
    for (int jj=0;jj<16;jj++){
      #pragma unroll
      for (int t=0;t<16;t++) acc[t] = fmaf(h[jj], w[(size_t)jj*ENCD + t], acc[t]);
    }
  }
  float* out = enc + (size_t)n*ENCD + k0;
  #pragma unroll
  for (int q=0;q<4;q++){ float4 v; v.x=acc[4*q]; v.y=acc[4*q+1]; v.z=acc[4*q+2]; v.w=acc[4*q+3]; st4(out+4*q, v); }
}

// h2 = relu(enc @ dW0 + db0), tiled h2t[tile][n][16]
__global__ __launch_bounds__(256) void k_dec1(const float* __restrict__ enc, const float* __restrict__ dW0,
    const float* __restrict__ db0, float* __restrict__ h2t){
  int n = blockIdx.x*256 + threadIdx.x;
  if (n >= NN) return;
  int j0 = blockIdx.y * 16;
  const float* xr = enc + (size_t)n*ENCD;
  float xv[ENCD];
  #pragma unroll
  for (int q=0;q<ENCD/4;q++){ float4 v = ld4(xr + 4*q); xv[4*q]=v.x; xv[4*q+1]=v.y; xv[4*q+2]=v.z; xv[4*q+3]=v.w; }
  float acc[16];
  #pragma unroll
  for (int t=0;t<16;t++) acc[t] = db0[j0+t];
  const float* w = dW0 + j0;
  #pragma unroll
  for (int d=0; d<ENCD; d++){
    #pragma unroll
    for (int t=0;t<16;t++) acc[t] = fmaf(xv[d], w[(size_t)d*H0 + t], acc[t]);
  }
  float* out = h2t + ((size_t)blockIdx.y * NN + n) * 16;
  #pragma unroll
  for (int q=0;q<4;q++){
    float4 v; v.x=fmaxf(acc[4*q],0.f); v.y=fmaxf(acc[4*q+1],0.f); v.z=fmaxf(acc[4*q+2],0.f); v.w=fmaxf(acc[4*q+3],0.f);
    st4(out + 4*q, v);
  }
}

// dec = h2 @ dW1 + db1 ; loss += sum((dec - emb)^2) / (NN*DD)
__global__ __launch_bounds__(256) void k_dec2(const float* __restrict__ h2t, const float* __restrict__ dW1,
    const float* __restrict__ db1, const float* __restrict__ ent, const float* __restrict__ usr,
    float* __restrict__ loss_out){
  int n = blockIdx.x*256 + threadIdx.x;
  int k0 = blockIdx.y * 16;
  float part = 0.f;
  if (n < NN){
    float acc[16];
    #pragma unroll
    for (int t=0;t<16;t++) acc[t] = db1[k0+t];
    for (int tj=0; tj<8; tj++){
      const float* hr = h2t + ((size_t)tj * NN + n) * 16;
      float h[16];
      #pragma unroll
      for (int q=0;q<4;q++){ float4 v = ld4(hr+4*q); h[4*q]=v.x; h[4*q+1]=v.y; h[4*q+2]=v.z; h[4*q+3]=v.w; }
      const float* w = dW1 + (size_t)tj*16*DD + k0;
      #pragma unroll
      for (int jj=0;jj<16;jj++){
        #pragma unroll
        for (int t=0;t<16;t++) acc[t] = fmaf(h[jj], w[(size_t)jj*DD + t], acc[t]);
      }
    }
    const float* xr = (n < N_ENT) ? (ent + (size_t)n*DD + k0) : (usr + (size_t)(n-N_ENT)*DD + k0);
    #pragma unroll
    for (int t=0;t<16;t++){ float d_ = acc[t] - xr[t]; part = fmaf(d_, d_, part); }
  }
  #pragma unroll
  for (int off=32; off>0; off>>=1) part += __shfl_down(part, off, 64);
  __shared__ float sred[4];
  if ((threadIdx.x & 63)==0) sred[threadIdx.x>>6] = part;
  __syncthreads();
  if (threadIdx.x==0){
    float s = (sred[0]+sred[1]+sred[2]+sred[3]) * (1.0f/((float)NN*(float)DD));
    atomicAdd(loss_out, s);
  }
}

__global__ __launch_bounds__(256) void k_hist(const int* __restrict__ edst, int* __restrict__ cnt, int E_){
  int e = blockIdx.x*256 + threadIdx.x;
  if (e >= E_) return;
  atomicAdd(&cnt[edst[e]], 1);
}

__global__ __launch_bounds__(256) void k_bsum(const int* __restrict__ cnt, int* __restrict__ bsum){
  int i = blockIdx.x*256 + threadIdx.x;
  int v = (i < NN) ? cnt[i] : 0;
  #pragma unroll
  for (int off=32; off>0; off>>=1) v += __shfl_down(v, off, 64);
  __shared__ int s[4];
  if ((threadIdx.x & 63)==0) s[threadIdx.x>>6] = v;
  __syncthreads();
  if (threadIdx.x==0) bsum[blockIdx.x] = s[0]+s[1]+s[2]+s[3];
}

__global__ __launch_bounds__(256) void k_scanb(int* __restrict__ bsum, int nb){
  __shared__ int s[256];
  int t = threadIdx.x;
  int v = (t < nb) ? bsum[t] : 0;
  s[t] = v;
  __syncthreads();
  #pragma unroll
  for (int off=1; off<256; off<<=1){
    int a = (t>=off) ? s[t-off] : 0;
    __syncthreads();
    s[t] += a;
    __syncthreads();
  }
  if (t < nb) bsum[t] = s[t] - v;   // exclusive block offsets
}

__global__ __launch_bounds__(256) void k_scanc(const int* __restrict__ cnt, const int* __restrict__ bsum,
                                               int* __restrict__ rowp){
  __shared__ int s[256];
  int t = threadIdx.x;
  int i = blockIdx.x*256 + t;
  int v = (i < NN) ? cnt[i] : 0;
  s[t] = v;
  __syncthreads();
  #pragma unroll
  for (int off=1; off<256; off<<=1){
    int a = (t>=off) ? s[t-off] : 0;
    __syncthreads();
    s[t] += a;
    __syncthreads();
  }
  if (i < NN) rowp[i+1] = bsum[blockIdx.x] + s[t];
  if (i == 0) rowp[0] = 0;
}

// CSR scatter: store src and rel packed into one word at the sorted slot
__global__ __launch_bounds__(256) void k_scatter(const int* __restrict__ esrc, const int* __restrict__ edst,
    const int* __restrict__ erel, const int* __restrict__ rowp, int* __restrict__ fill,
    int* __restrict__ packed, int E_){
  int e = blockIdx.x*256 + threadIdx.x;
  if (e >= E_) return;
  int d_ = edst[e];
  int p = rowp[d_] + atomicAdd(&fill[d_], 1);
  packed[p] = esrc[e] | (erel[e] << 20);
}

// Per-node, per-relation partial gate dots: dA[n][r] = x[n].wsum[r][0:32], dB[n][r] = x[n].wsum[r][32:64]
__global__ __launch_bounds__(256) void k_dots(const float* __restrict__ x, const float* __restrict__ wsum,
    float* __restrict__ dA, float* __restrict__ dB){
  __shared__ float wl[RR*DD];                  // wl[j*16+rel] = wsum[rel*64+j]
  for (int i = threadIdx.x; i < RR*DD; i += 256){
    int r = i & 15; int j = i >> 4;
    wl[i] = wsum[r*DD + j];
  }
  __syncthreads();
  int t = blockIdx.x*256 + threadIdx.x;
  if (t >= NN*RR) return;
  int n = t >> 4, r = t & 15;
  const float* xr = x + (size_t)n*ENCD;
  float a = 0.f, b = 0.f;
  #pragma unroll
  for (int q=0;q<8;q++){
    float4 v = ld4(xr + 4*q);
    int j = 4*q;
    a = fmaf(v.x, wl[(j+0)*16 + r], a);
    a = fmaf(v.y, wl[(j+1)*16 + r], a);
    a = fmaf(v.z, wl[(j+2)*16 + r], a);
    a = fmaf(v.w, wl[(j+3)*16 + r], a);
    b = fmaf(v.x, wl[(32+j+0)*16 + r], b);
    b = fmaf(v.y, wl[(32+j+1)*16 + r], b);
    b = fmaf(v.z, wl[(32+j+2)*16 + r], b);
    b = fmaf(v.w, wl[(32+j+3)*16 + r], b);
  }
  dA[t] = a;
  dB[t] = b;
}

// Fused gate + scatter-mean via CSR gather: 32 lanes per node
__global__ __launch_bounds__(256) void k_agg(const float* __restrict__ x, const int* __restrict__ packed,
    const int* __restrict__ rowp, const float* __restrict__ dA, const float* __restrict__ dB,
    float* __restrict__ agg){
  int node = blockIdx.x*8 + (threadIdx.x >> 5);
  int f = threadIdx.x & 31;
  if (node >= NN) return;
  float dv = dA[node*16 + (f & 15)];           // lane r holds dA[node][r]
  int beg = rowp[node], end = rowp[node+1];
  float acc = 0.f;
  #pragma unroll 2
  for (int i = beg; i < end; i++){
    int p = packed[i];
    int s = p & 0xFFFFF;
    int r = p >> 20;
    float z = __shfl(dv, r, 32) + dB[s*16 + r];
    float g = 1.f / (1.f + __expf(-z));
    acc = fmaf(x[(size_t)s*ENCD + f], g, acc);
  }
  int deg = end - beg;
  agg[(size_t)node*ENCD + f] = (deg > 0) ? (acc / (float)deg) : 0.f;
}

// out = leaky_relu(concat(x,agg) @ W + b), W is [64][outd]
__global__ __launch_bounds__(256) void k_lin(const float* __restrict__ x, const float* __restrict__ agg,
    const float* __restrict__ W, const float* __restrict__ b, float* __restrict__ out, int outd){
  int n = blockIdx.x*256 + threadIdx.x;
  if (n >= NN) return;
  int k0 = blockIdx.y * 16;
  const float* xr = x   + (size_t)n*ENCD;
  const float* ar = agg + (size_t)n*ENCD;
  float xv[32], av[32];
  #pragma unroll
  for (int q=0;q<8;q++){ float4 v = ld4(xr+4*q); xv[4*q]=v.x; xv[4*q+1]=v.y; xv[4*q+2]=v.z; xv[4*q+3]=v.w; }
  #pragma unroll
  for (int q=0;q<8;q++){ float4 v = ld4(ar+4*q); av[4*q]=v.x; av[4*q+1]=v.y; av[4*q+2]=v.z; av[4*q+3]=v.w; }
  float acc[16];
  #pragma unroll
  for (int t=0;t<16;t++) acc[t] = b[k0+t];
  #pragma unroll
  for (int j=0;j<32;j++){
    #pragma unroll
    for (int t=0;t<16;t++) acc[t] = fmaf(xv[j], W[(size_t)j*outd + k0 + t], acc[t]);
  }
  #pragma unroll
  for (int j=0;j<32;j++){
    #pragma unroll
    for (int t=0;t<16;t++) acc[t] = fmaf(av[j], W[(size_t)(32+j)*outd + k0 + t], acc[t]);
  }
  float* o = out + (size_t)n*outd + k0;
  #pragma unroll
  for (int q=0;q<4;q++){
    float4 v;
    float a0=acc[4*q],a1=acc[4*q+1],a2=acc[4*q+2],a3=acc[4*q+3];
    v.x = a0>0.f? a0 : 0.01f*a0;
    v.y = a1>0.f? a1 : 0.01f*a1;
    v.z = a2>0.f? a2 : 0.01f*a2;
    v.w = a3>0.f? a3 : 0.01f*a3;
    st4(o + 4*q, v);
  }
}

__global__ __launch_bounds__(256) void k_score(const float* __restrict__ x1, const float* __restrict__ x2,
    const int* __restrict__ users, const int* __restrict__ items, float* __restrict__ out, int Bn){
  int b = blockIdx.x*256 + threadIdx.x;
  if (b >= Bn) return;
  int u  = N_ENT + users[b];
  int it = items[b];
  const float* a1 = x1 + (size_t)u*32;
  const float* c1 = x1 + (size_t)it*32;
  const float* a2 = x2 + (size_t)u*16;
  const float* c2 = x2 + (size_t)it*16;
  float s = 0.f;
  #pragma unroll
  for (int q=0;q<8;q++){
    float4 va=ld4(a1+4*q), vb=ld4(c1+4*q);
    s = fmaf(va.x,vb.x,s); s = fmaf(va.y,vb.y,s); s = fmaf(va.z,vb.z,s); s = fmaf(va.w,vb.w,s);
  }
  #pragma unroll
  for (int q=0;q<4;q++){
    float4 va=ld4(a2+4*q), vb=ld4(c2+4*q);
    s = fmaf(va.x,vb.x,s); s = fmaf(va.y,vb.y,s); s = fmaf(va.z,vb.z,s); s = fmaf(va.w,vb.w,s);
  }
  out[b] = s;
}

extern "C" void kernel_launch(void* const* d_in, const int* in_sizes, int n_in,
                              void* d_out, int out_size, void* d_ws, size_t ws_size,
                              hipStream_t stream){
  const int*   users   = (const int*)d_in[0];
  const int*   items   = (const int*)d_in[1];
  const int*   esrc    = (const int*)d_in[2];
  const int*   edst    = (const int*)d_in[3];
  const int*   erel    = (const int*)d_in[4];
  const float* ent     = (const float*)d_in[5];
  const float* usr     = (const float*)d_in[6];
  const float* enc_W0  = (const float*)d_in[7];
  const float* enc_b0  = (const float*)d_in[8];
  const float* enc_W1  = (const float*)d_in[9];
  const float* enc_b1  = (const float*)d_in[10];
  const float* dec_W0  = (const float*)d_in[11];
  const float* dec_b0  = (const float*)d_in[12];
  const float* dec_W1  = (const float*)d_in[13];
  const float* dec_b1  = (const float*)d_in[14];
  const float* Wr1     = (const float*)d_in[15];
  const float* lin_W1  = (const float*)d_in[16];
  const float* lin_b1  = (const float*)d_in[17];
  const float* Wr2     = (const float*)d_in[18];
  const float* lin_W2  = (const float*)d_in[19];
  const float* lin_b2  = (const float*)d_in[20];
  const int E = in_sizes[2];
  const int B = in_sizes[0];

  char* wp = (char*)d_ws;
  auto carve = [&](size_t bytes)->char*{ char* p = wp; wp += (bytes + 255) & ~(size_t)255; return p; };
  float* enc    = (float*)carve((size_t)NN*32*4);
  float* x1     = (float*)carve((size_t)NN*32*4);
  float* x2     = (float*)carve((size_t)NN*16*4);
  float* agg    = (float*)carve((size_t)NN*32*4);
  float* h1t    = (float*)carve((size_t)NN*128*4);   // reused for h2t
  float* wsum   = (float*)carve((size_t)2*RR*DD*4);
  float* dA     = (float*)carve((size_t)NN*RR*4);
  float* dB     = (float*)carve((size_t)NN*RR*4);
  int*   packed = (int*)  carve((size_t)E*4);
  int*   cnt    = (int*)  carve((size_t)2*NN*4);     // cnt then fill, one memset
  int*   fill   = cnt + NN;
  int*   rowp   = (int*)  carve(((size_t)NN+1)*4);
  int*   bsum   = (int*)  carve(256*4);

  const int nbN = (NN + 255)/256;   // 235
  const int nbE = (E  + 255)/256;
  const int nbD = (NN*RR + 255)/256;
  dim3 blk(256);

  hipMemsetAsync(d_out, 0, (size_t)out_size*sizeof(float), stream);
  hipMemsetAsync(cnt, 0, (size_t)2*NN*sizeof(int), stream);

  k_wsum <<<dim3((2*RR*DD+255)/256), blk, 0, stream>>>(Wr1, Wr2, wsum);
  k_enc1 <<<dim3(nbN, 8), blk, 0, stream>>>(ent, usr, enc_W0, enc_b0, h1t);
  k_enc2 <<<dim3(nbN, 2), blk, 0, stream>>>(h1t, enc_W1, enc_b1, enc);
  k_dec1 <<<dim3(nbN, 8), blk, 0, stream>>>(enc, dec_W0, dec_b0, h1t);
  k_dec2 <<<dim3(nbN, 4), blk, 0, stream>>>(h1t, dec_W1, dec_b1, ent, usr, ((float*)d_out) + B);

  k_hist   <<<nbE, blk, 0, stream>>>(edst, cnt, E);
  k_bsum   <<<nbN, blk, 0, stream>>>(cnt, bsum);
  k_scanb  <<<1,   blk, 0, stream>>>(bsum, nbN);
  k_scanc  <<<nbN, blk, 0, stream>>>(cnt, bsum, rowp);
  k_scatter<<<nbE, blk, 0, stream>>>(esrc, edst, erel, rowp, fill, packed, E);

  k_dots <<<nbD, blk, 0, stream>>>(enc, wsum, dA, dB);
  k_agg  <<<(NN+7)/8, blk, 0, stream>>>(enc, packed, rowp, dA, dB, agg);
  k_lin  <<<dim3(nbN, 2), blk, 0, stream>>>(enc, agg, lin_W1, lin_b1, x1, 32);

  k_dots <<<nbD, blk, 0, stream>>>(x1, wsum + RR*DD, dA, dB);
  k_agg  <<<(NN+7)/8, blk, 0, stream>>>(x1, packed, rowp, dA, dB, agg);
  k_lin  <<<dim3(nbN, 1), blk, 0, stream>>>(x1, agg, lin_W2, lin_b2, x2, 16);

  k_score<<<(B+255)/256, blk, 0, stream>>>(x1, x2, users, items, (float*)d_out, B);
}

// Round 4
// 573.139 us; speedup vs baseline: 1.4098x; 1.2017x over previous
//
#include <hip/hip_runtime.h>
#include <math.h>

#define N_ENT 50000
#define N_USR 10000
#define NN    60000
#define DD    64
#define H0    128
#define ENCD  32
#define RR    16
#define NB    64
#define BSH   10

__device__ __forceinline__ float4 ld4(const float* p){ return *reinterpret_cast<const float4*>(p); }
__device__ __forceinline__ void st4(float* p, float4 v){ *reinterpret_cast<float4*>(p) = v; }

// w_sum[layer][r*64+j] = sum_k Wr[r][j][k]
__global__ __launch_bounds__(256) void k_wsum(const float* __restrict__ Wr1, const float* __restrict__ Wr2,
                                              float* __restrict__ wsum){
  int i = blockIdx.x*256 + threadIdx.x;        // 0..2047
  if (i >= 2*RR*DD) return;
  const float* Wr = (i < RR*DD) ? Wr1 : Wr2;
  int loc = i & (RR*DD - 1);                   // r*64+j
  const float* p = Wr + (size_t)loc*32;
  float s = 0.f;
  #pragma unroll
  for (int k=0;k<32;k++) s += p[k];
  wsum[i] = s;
}

// h1 = relu(emb @ W0 + b0), stored tiled: h1t[tile][n][16]
__global__ __launch_bounds__(256) void k_enc1(const float* __restrict__ ent, const float* __restrict__ usr,
    const float* __restrict__ W0, const float* __restrict__ b0, float* __restrict__ h1t){
  int n = blockIdx.x*256 + threadIdx.x;
  if (n >= NN) return;
  int j0 = blockIdx.y * 16;
  const float* xr = (n < N_ENT) ? (ent + (size_t)n*DD) : (usr + (size_t)(n-N_ENT)*DD);
  float xv[DD];
  #pragma unroll
  for (int q=0;q<DD/4;q++){ float4 v = ld4(xr + 4*q); xv[4*q]=v.x; xv[4*q+1]=v.y; xv[4*q+2]=v.z; xv[4*q+3]=v.w; }
  float acc[16];
  #pragma unroll
  for (int t=0;t<16;t++) acc[t] = b0[j0+t];
  const float* w = W0 + j0;
  #pragma unroll
  for (int d=0; d<DD; d++){
    #pragma unroll
    for (int t=0;t<16;t++) acc[t] = fmaf(xv[d], w[(size_t)d*H0 + t], acc[t]);
  }
  float* out = h1t + ((size_t)blockIdx.y * NN + n) * 16;
  #pragma unroll
  for (int q=0;q<4;q++){
    float4 v; v.x=fmaxf(acc[4*q],0.f); v.y=fmaxf(acc[4*q+1],0.f); v.z=fmaxf(acc[4*q+2],0.f); v.w=fmaxf(acc[4*q+3],0.f);
    st4(out + 4*q, v);
  }
}

// enc = h1 @ W1 + b1   (no activation), enc row-major [NN][32]
__global__ __launch_bounds__(256) void k_enc2(const float* __restrict__ h1t, const float* __restrict__ W1,
    const float* __restrict__ b1, float* __restrict__ enc){
  int n = blockIdx.x*256 + threadIdx.x;
  if (n >= NN) return;
  int k0 = blockIdx.y * 16;
  float acc[16];
  #pragma unroll
  for (int t=0;t<16;t++) acc[t] = b1[k0+t];
  for (int tj=0; tj<8; tj++){
    const float* hr = h1t + ((size_t)tj * NN + n) * 16;
    float h[16];
    #pragma unroll
    for (int q=0;q<4;q++){ float4 v = ld4(hr+4*q); h[4*q]=v.x; h[4*q+1]=v.y; h[4*q+2]=v.z; h[4*q+3]=v.w; }
    const float* w = W1 + (size_t)tj*16*ENCD + k0;
    #pragma unroll
    for (int jj=0;jj<16;jj++){
      #pragma unroll
      for (int t=0;t<16;t++) acc[t] = fmaf(h[jj], w[(size_t)jj*ENCD + t], acc[t]);
    }
  }
  float* out = enc + (size_t)n*ENCD + k0;
  #pragma unroll
  for (int q=0;q<4;q++){ float4 v; v.x=acc[4*q]; v.y=acc[4*q+1]; v.z=acc[4*q+2]; v.w=acc[4*q+3]; st4(out+4*q, v); }
}

// h2 = relu(enc @ dW0 + db0), tiled h2t[tile][n][16]
__global__ __launch_bounds__(256) void k_dec1(const float* __restrict__ enc, const float* __restrict__ dW0,
    const float* __restrict__ db0, float* __restrict__ h2t){
  int n = blockIdx.x*256 + threadIdx.x;
  if (n >= NN) return;
  int j0 = blockIdx.y * 16;
  const float* xr = enc + (size_t)n*ENCD;
  float xv[ENCD];
  #pragma unroll
  for (int q=0;q<ENCD/4;q++){ float4 v = ld4(xr + 4*q); xv[4*q]=v.x; xv[4*q+1]=v.y; xv[4*q+2]=v.z; xv[4*q+3]=v.w; }
  float acc[16];
  #pragma unroll
  for (int t=0;t<16;t++) acc[t] = db0[j0+t];
  const float* w = dW0 + j0;
  #pragma unroll
  for (int d=0; d<ENCD; d++){
    #pragma unroll
    for (int t=0;t<16;t++) acc[t] = fmaf(xv[d], w[(size_t)d*H0 + t], acc[t]);
  }
  float* out = h2t + ((size_t)blockIdx.y * NN + n) * 16;
  #pragma unroll
  for (int q=0;q<4;q++){
    float4 v; v.x=fmaxf(acc[4*q],0.f); v.y=fmaxf(acc[4*q+1],0.f); v.z=fmaxf(acc[4*q+2],0.f); v.w=fmaxf(acc[4*q+3],0.f);
    st4(out + 4*q, v);
  }
}

// dec = h2 @ dW1 + db1 ; loss += sum((dec - emb)^2) / (NN*DD)
__global__ __launch_bounds__(256) void k_dec2(const float* __restrict__ h2t, const float* __restrict__ dW1,
    const float* __restrict__ db1, const float* __restrict__ ent, const float* __restrict__ usr,
    float* __restrict__ loss_out){
  int n = blockIdx.x*256 + threadIdx.x;
  int k0 = blockIdx.y * 16;
  float part = 0.f;
  if (n < NN){
    float acc[16];
    #pragma unroll
    for (int t=0;t<16;t++) acc[t] = db1[k0+t];
    for (int tj=0; tj<8; tj++){
      const float* hr = h2t + ((size_t)tj * NN + n) * 16;
      float h[16];
      #pragma unroll
      for (int q=0;q<4;q++){ float4 v = ld4(hr+4*q); h[4*q]=v.x; h[4*q+1]=v.y; h[4*q+2]=v.z; h[4*q+3]=v.w; }
      const float* w = dW1 + (size_t)tj*16*DD + k0;
      #pragma unroll
      for (int jj=0;jj<16;jj++){
        #pragma unroll
        for (int t=0;t<16;t++) acc[t] = fmaf(h[jj], w[(size_t)jj*DD + t], acc[t]);
      }
    }
    const float* xr = (n < N_ENT) ? (ent + (size_t)n*DD + k0) : (usr + (size_t)(n-N_ENT)*DD + k0);
    #pragma unroll
    for (int t=0;t<16;t++){ float d_ = acc[t] - xr[t]; part = fmaf(d_, d_, part); }
  }
  #pragma unroll
  for (int off=32; off>0; off>>=1) part += __shfl_down(part, off, 64);
  __shared__ float sred[4];
  if ((threadIdx.x & 63)==0) sred[threadIdx.x>>6] = part;
  __syncthreads();
  if (threadIdx.x==0){
    float s = (sred[0]+sred[1]+sred[2]+sred[3]) * (1.0f/((float)NN*(float)DD));
    atomicAdd(loss_out, s);
  }
}

// 64-bucket histogram of edge destinations
__global__ __launch_bounds__(256) void k_hist64(const int* __restrict__ edst, int* __restrict__ bktCnt, int E_){
  __shared__ int h[NB];
  for (int i=threadIdx.x; i<NB; i+=256) h[i]=0;
  __syncthreads();
  int i0 = blockIdx.x*4096;
  #pragma unroll
  for (int k=0;k<16;k++){
    int e = i0 + k*256 + threadIdx.x;
    if (e < E_) atomicAdd(&h[((unsigned)edst[e])>>BSH], 1);
  }
  __syncthreads();
  for (int i=threadIdx.x; i<NB; i+=256) if (h[i]) atomicAdd(&bktCnt[i], h[i]);
}

// exclusive scan of 64 bucket counts (single wave)
__global__ __launch_bounds__(64) void k_scan64(const int* __restrict__ bktCnt, int* __restrict__ bktBase){
  int t = threadIdx.x;
  int v = bktCnt[t];
  int x = v;
  #pragma unroll
  for (int off=1; off<64; off<<=1){
    int y = __shfl_up(x, off, 64);
    if (t >= off) x += y;
  }
  bktBase[t] = x - v;
}

// bucketed append: each block reserves exclusive contiguous chunks per bucket
__global__ __launch_bounds__(256) void k_bucketA(const int* __restrict__ esrc, const int* __restrict__ edst,
    const int* __restrict__ erel, const int* __restrict__ bktBase, int* __restrict__ bktFill,
    unsigned* __restrict__ bktData, int E_){
  __shared__ int h[NB];
  __shared__ int gbase[NB];
  for (int i=threadIdx.x; i<NB; i+=256) h[i]=0;
  __syncthreads();
  int i0 = blockIdx.x*4096;
  int dcache[16];
  #pragma unroll
  for (int k=0;k<16;k++){
    int e = i0 + k*256 + threadIdx.x;
    int d = (e < E_) ? edst[e] : -1;
    dcache[k] = d;
    if (d >= 0) atomicAdd(&h[((unsigned)d)>>BSH], 1);
  }
  __syncthreads();
  if (threadIdx.x < NB){
    int c = h[threadIdx.x];
    int off = c ? atomicAdd(&bktFill[threadIdx.x], c) : 0;
    gbase[threadIdx.x] = bktBase[threadIdx.x] + off;
    h[threadIdx.x] = 0;   // reuse as local fill
  }
  __syncthreads();
  #pragma unroll
  for (int k=0;k<16;k++){
    int e = i0 + k*256 + threadIdx.x;
    if (e >= E_) continue;
    int d = dcache[k];
    int b = ((unsigned)d) >> BSH;
    int slot = atomicAdd(&h[b], 1);
    unsigned rec = (unsigned)esrc[e] | ((unsigned)erel[e] << 16) | ((unsigned)(d & ((1<<BSH)-1)) << 20);
    bktData[(size_t)gbase[b] + slot] = rec;
  }
}

// per-bucket CSR build: counts+scan in LDS, localized writes
__global__ __launch_bounds__(1024) void k_buildB(const unsigned* __restrict__ bktData,
    const int* __restrict__ bktBase, const int* __restrict__ bktCnt,
    int* __restrict__ rowp, int* __restrict__ packed){
  __shared__ int cnt[1024];
  __shared__ int start[1024];
  __shared__ int wps[16];
  int b = blockIdx.x;
  int base = bktBase[b];
  int n = bktCnt[b];
  int t = threadIdx.x;
  cnt[t] = 0;
  __syncthreads();
  for (int i=t; i<n; i+=1024) atomicAdd(&cnt[bktData[base+i] >> 20], 1);
  __syncthreads();
  int v = cnt[t];
  cnt[t] = 0;                       // reset for fill pass
  int x = v;
  #pragma unroll
  for (int off=1; off<64; off<<=1){
    int y = __shfl_up(x, off, 64);
    if ((t & 63) >= off) x += y;
  }
  if ((t & 63) == 63) wps[t >> 6] = x;
  __syncthreads();
  if (t < 16){
    int wv = wps[t];
    int wx = wv;
    #pragma unroll
    for (int off=1; off<16; off<<=1){
      int y = __shfl_up(wx, off, 16);
      if (t >= off) wx += y;
    }
    wps[t] = wx - wv;               // exclusive wave prefix
  }
  __syncthreads();
  int sv = (x - v) + wps[t >> 6];   // exclusive prefix over dl
  start[t] = sv;
  int node = (b << BSH) + t;
  if (node <= NN) rowp[node] = base + sv;   // node==NN lands in bucket 58 @ t=608 -> rowp[NN]=E
  __syncthreads();
  for (int i=t; i<n; i+=1024){
    unsigned r = bktData[base+i];
    int dl = r >> 20;
    int p = start[dl] + atomicAdd(&cnt[dl], 1);
    packed[base + p] = (int)(r & 0xFFFFF);
  }
}

// Per-node, per-relation partial gate dots: dA[n][r] = x[n].wsum[r][0:32], dB[n][r] = x[n].wsum[r][32:64]
__global__ __launch_bounds__(256) void k_dots(const float* __restrict__ x, const float* __restrict__ wsum,
    float* __restrict__ dA, float* __restrict__ dB){
  __shared__ float wl[RR*DD];                  // wl[j*16+rel] = wsum[rel*64+j]
  for (int i = threadIdx.x; i < RR*DD; i += 256){
    int r = i & 15; int j = i >> 4;
    wl[i] = wsum[r*DD + j];
  }
  __syncthreads();
  int t = blockIdx.x*256 + threadIdx.x;
  if (t >= NN*RR) return;
  int n = t >> 4, r = t & 15;
  const float* xr = x + (size_t)n*ENCD;
  float a = 0.f, b = 0.f;
  #pragma unroll
  for (int q=0;q<8;q++){
    float4 v = ld4(xr + 4*q);
    int j = 4*q;
    a = fmaf(v.x, wl[(j+0)*16 + r], a);
    a = fmaf(v.y, wl[(j+1)*16 + r], a);
    a = fmaf(v.z, wl[(j+2)*16 + r], a);
    a = fmaf(v.w, wl[(j+3)*16 + r], a);
    b = fmaf(v.x, wl[(32+j+0)*16 + r], b);
    b = fmaf(v.y, wl[(32+j+1)*16 + r], b);
    b = fmaf(v.z, wl[(32+j+2)*16 + r], b);
    b = fmaf(v.w, wl[(32+j+3)*16 + r], b);
  }
  dA[t] = a;
  dB[t] = b;
}

// Fused gate + scatter-mean via CSR gather: 32 lanes per node
__global__ __launch_bounds__(256) void k_agg(const float* __restrict__ x, const int* __restrict__ packed,
    const int* __restrict__ rowp, const float* __restrict__ dA, const float* __restrict__ dB,
    float* __restrict__ agg){
  int node = blockIdx.x*8 + (threadIdx.x >> 5);
  int f = threadIdx.x & 31;
  if (node >= NN) return;
  float dv = dA[node*16 + (f & 15)];           // lane r holds dA[node][r]
  int beg = rowp[node], end = rowp[node+1];
  float acc = 0.f;
  #pragma unroll 2
  for (int i = beg; i < end; i++){
    int p = packed[i];
    int s = p & 0xFFFF;
    int r = (p >> 16) & 15;
    float z = __shfl(dv, r, 32) + dB[s*16 + r];
    float g = 1.f / (1.f + __expf(-z));
    acc = fmaf(x[(size_t)s*ENCD + f], g, acc);
  }
  int deg = end - beg;
  agg[(size_t)node*ENCD + f] = (deg > 0) ? (acc / (float)deg) : 0.f;
}

// out = leaky_relu(concat(x,agg) @ W + b), W is [64][outd]
__global__ __launch_bounds__(256) void k_lin(const float* __restrict__ x, const float* __restrict__ agg,
    const float* __restrict__ W, const float* __restrict__ b, float* __restrict__ out, int outd){
  int n = blockIdx.x*256 + threadIdx.x;
  if (n >= NN) return;
  int k0 = blockIdx.y * 16;
  const float* xr = x   + (size_t)n*ENCD;
  const float* ar = agg + (size_t)n*ENCD;
  float xv[32], av[32];
  #pragma unroll
  for (int q=0;q<8;q++){ float4 v = ld4(xr+4*q); xv[4*q]=v.x; xv[4*q+1]=v.y; xv[4*q+2]=v.z; xv[4*q+3]=v.w; }
  #pragma unroll
  for (int q=0;q<8;q++){ float4 v = ld4(ar+4*q); av[4*q]=v.x; av[4*q+1]=v.y; av[4*q+2]=v.z; av[4*q+3]=v.w; }
  float acc[16];
  #pragma unroll
  for (int t=0;t<16;t++) acc[t] = b[k0+t];
  #pragma unroll
  for (int j=0;j<32;j++){
    #pragma unroll
    for (int t=0;t<16;t++) acc[t] = fmaf(xv[j], W[(size_t)j*outd + k0 + t], acc[t]);
  }
  #pragma unroll
  for (int j=0;j<32;j++){
    #pragma unroll
    for (int t=0;t<16;t++) acc[t] = fmaf(av[j], W[(size_t)(32+j)*outd + k0 + t], acc[t]);
  }
  float* o = out + (size_t)n*outd + k0;
  #pragma unroll
  for (int q=0;q<4;q++){
    float4 v;
    float a0=acc[4*q],a1=acc[4*q+1],a2=acc[4*q+2],a3=acc[4*q+3];
    v.x = a0>0.f? a0 : 0.01f*a0;
    v.y = a1>0.f? a1 : 0.01f*a1;
    v.z = a2>0.f? a2 : 0.01f*a2;
    v.w = a3>0.f? a3 : 0.01f*a3;
    st4(o + 4*q, v);
  }
}

__global__ __launch_bounds__(256) void k_score(const float* __restrict__ x1, const float* __restrict__ x2,
    const int* __restrict__ users, const int* __restrict__ items, float* __restrict__ out, int Bn){
  int b = blockIdx.x*256 + threadIdx.x;
  if (b >= Bn) return;
  int u  = N_ENT + users[b];
  int it = items[b];
  const float* a1 = x1 + (size_t)u*32;
  const float* c1 = x1 + (size_t)it*32;
  const float* a2 = x2 + (size_t)u*16;
  const float* c2 = x2 + (size_t)it*16;
  float s = 0.f;
  #pragma unroll
  for (int q=0;q<8;q++){
    float4 va=ld4(a1+4*q), vb=ld4(c1+4*q);
    s = fmaf(va.x,vb.x,s); s = fmaf(va.y,vb.y,s); s = fmaf(va.z,vb.z,s); s = fmaf(va.w,vb.w,s);
  }
  #pragma unroll
  for (int q=0;q<4;q++){
    float4 va=ld4(a2+4*q), vb=ld4(c2+4*q);
    s = fmaf(va.x,vb.x,s); s = fmaf(va.y,vb.y,s); s = fmaf(va.z,vb.z,s); s = fmaf(va.w,vb.w,s);
  }
  out[b] = s;
}

extern "C" void kernel_launch(void* const* d_in, const int* in_sizes, int n_in,
                              void* d_out, int out_size, void* d_ws, size_t ws_size,
                              hipStream_t stream){
  const int*   users   = (const int*)d_in[0];
  const int*   items   = (const int*)d_in[1];
  const int*   esrc    = (const int*)d_in[2];
  const int*   edst    = (const int*)d_in[3];
  const int*   erel    = (const int*)d_in[4];
  const float* ent     = (const float*)d_in[5];
  const float* usr     = (const float*)d_in[6];
  const float* enc_W0  = (const float*)d_in[7];
  const float* enc_b0  = (const float*)d_in[8];
  const float* enc_W1  = (const float*)d_in[9];
  const float* enc_b1  = (const float*)d_in[10];
  const float* dec_W0  = (const float*)d_in[11];
  const float* dec_b0  = (const float*)d_in[12];
  const float* dec_W1  = (const float*)d_in[13];
  const float* dec_b1  = (const float*)d_in[14];
  const float* Wr1     = (const float*)d_in[15];
  const float* lin_W1  = (const float*)d_in[16];
  const float* lin_b1  = (const float*)d_in[17];
  const float* Wr2     = (const float*)d_in[18];
  const float* lin_W2  = (const float*)d_in[19];
  const float* lin_b2  = (const float*)d_in[20];
  const int E = in_sizes[2];
  const int B = in_sizes[0];

  char* wp = (char*)d_ws;
  auto carve = [&](size_t bytes)->char*{ char* p = wp; wp += (bytes + 255) & ~(size_t)255; return p; };
  float* enc    = (float*)carve((size_t)NN*32*4);
  float* x1     = (float*)carve((size_t)NN*32*4);
  float* x2     = (float*)carve((size_t)NN*16*4);
  float* agg    = (float*)carve((size_t)NN*32*4);
  float* h1t    = (float*)carve((size_t)NN*128*4);   // reused: h2t, then bktData
  float* wsum   = (float*)carve((size_t)2*RR*DD*4);
  float* dA     = (float*)carve((size_t)NN*RR*4);
  float* dB     = (float*)carve((size_t)NN*RR*4);
  int*   packed = (int*)  carve((size_t)E*4);
  int*   bktCnt = (int*)  carve(128*4);              // bktCnt[64] + bktFill[64], one memset
  int*   bktFill= bktCnt + NB;
  int*   bktBase= (int*)  carve(NB*4);
  int*   rowp   = (int*)  carve(((size_t)NN+1)*4);
  unsigned* bktData = (unsigned*)h1t;                // alias: used only after dec path done

  const int nbN = (NN + 255)/256;   // 235
  const int nbT = (E + 4095)/4096;  // 4096-edge tiles
  const int nbD = (NN*RR + 255)/256;
  dim3 blk(256);

  hipMemsetAsync(d_out, 0, (size_t)out_size*sizeof(float), stream);
  hipMemsetAsync(bktCnt, 0, 128*sizeof(int), stream);

  k_wsum <<<dim3((2*RR*DD+255)/256), blk, 0, stream>>>(Wr1, Wr2, wsum);
  k_enc1 <<<dim3(nbN, 8), blk, 0, stream>>>(ent, usr, enc_W0, enc_b0, h1t);
  k_enc2 <<<dim3(nbN, 2), blk, 0, stream>>>(h1t, enc_W1, enc_b1, enc);
  k_dec1 <<<dim3(nbN, 8), blk, 0, stream>>>(enc, dec_W0, dec_b0, h1t);
  k_dec2 <<<dim3(nbN, 4), blk, 0, stream>>>(h1t, dec_W1, dec_b1, ent, usr, ((float*)d_out) + B);

  // CSR build via 64-bucket two-phase counting sort (h1t dead now; bktData aliases it)
  k_hist64 <<<nbT, blk, 0, stream>>>(edst, bktCnt, E);
  k_scan64 <<<1, dim3(64), 0, stream>>>(bktCnt, bktBase);
  k_bucketA<<<nbT, blk, 0, stream>>>(esrc, edst, erel, bktBase, bktFill, bktData, E);
  k_buildB <<<NB, dim3(1024), 0, stream>>>(bktData, bktBase, bktCnt, rowp, packed);

  k_dots <<<nbD, blk, 0, stream>>>(enc, wsum, dA, dB);
  k_agg  <<<(NN+7)/8, blk, 0, stream>>>(enc, packed, rowp, dA, dB, agg);
  k_lin  <<<dim3(nbN, 2), blk, 0, stream>>>(enc, agg, lin_W1, lin_b1, x1, 32);

  k_dots <<<nbD, blk, 0, stream>>>(x1, wsum + RR*DD, dA, dB);
  k_agg  <<<(NN+7)/8, blk, 0, stream>>>(x1, packed, rowp, dA, dB, agg);
  k_lin  <<<dim3(nbN, 1), blk, 0, stream>>>(x1, agg, lin_W2, lin_b2, x2, 16);

  k_score<<<(B+255)/256, blk, 0, stream>>>(x1, x2, users, items, (float*)d_out, B);
}

// Round 5
// 485.598 us; speedup vs baseline: 1.6640x; 1.1803x over previous
//
#include <hip/hip_runtime.h>
#include <hip/hip_fp16.h>
#include <math.h>

#define N_ENT 50000
#define N_USR 10000
#define NN    60000
#define DD    64
#define H0    128
#define ENCD  32
#define RR    16
#define NB    64
#define BSH   10

__device__ __forceinline__ float4 ld4(const float* p){ return *reinterpret_cast<const float4*>(p); }
__device__ __forceinline__ void st4(float* p, float4 v){ *reinterpret_cast<float4*>(p) = v; }

// w_sum[layer][r*64+j] = sum_k Wr[r][j][k]
__global__ __launch_bounds__(256) void k_wsum(const float* __restrict__ Wr1, const float* __restrict__ Wr2,
                                              float* __restrict__ wsum){
  int i = blockIdx.x*256 + threadIdx.x;        // 0..2047
  if (i >= 2*RR*DD) return;
  const float* Wr = (i < RR*DD) ? Wr1 : Wr2;
  int loc = i & (RR*DD - 1);                   // r*64+j
  const float* p = Wr + (size_t)loc*32;
  float s = 0.f;
  #pragma unroll
  for (int k=0;k<32;k++) s += p[k];
  wsum[i] = s;
}

// h1 = relu(emb @ W0 + b0), stored tiled: h1t[tile][n][16]
__global__ __launch_bounds__(256) void k_enc1(const float* __restrict__ ent, const float* __restrict__ usr,
    const float* __restrict__ W0, const float* __restrict__ b0, float* __restrict__ h1t){
  int n = blockIdx.x*256 + threadIdx.x;
  if (n >= NN) return;
  int j0 = blockIdx.y * 16;
  const float* xr = (n < N_ENT) ? (ent + (size_t)n*DD) : (usr + (size_t)(n-N_ENT)*DD);
  float xv[DD];
  #pragma unroll
  for (int q=0;q<DD/4;q++){ float4 v = ld4(xr + 4*q); xv[4*q]=v.x; xv[4*q+1]=v.y; xv[4*q+2]=v.z; xv[4*q+3]=v.w; }
  float acc[16];
  #pragma unroll
  for (int t=0;t<16;t++) acc[t] = b0[j0+t];
  const float* w = W0 + j0;
  #pragma unroll
  for (int d=0; d<DD; d++){
    #pragma unroll
    for (int t=0;t<16;t++) acc[t] = fmaf(xv[d], w[(size_t)d*H0 + t], acc[t]);
  }
  float* out = h1t + ((size_t)blockIdx.y * NN + n) * 16;
  #pragma unroll
  for (int q=0;q<4;q++){
    float4 v; v.x=fmaxf(acc[4*q],0.f); v.y=fmaxf(acc[4*q+1],0.f); v.z=fmaxf(acc[4*q+2],0.f); v.w=fmaxf(acc[4*q+3],0.f);
    st4(out + 4*q, v);
  }
}

// enc = h1 @ W1 + b1   (no activation), enc row-major [NN][32]
__global__ __launch_bounds__(256) void k_enc2(const float* __restrict__ h1t, const float* __restrict__ W1,
    const float* __restrict__ b1, float* __restrict__ enc){
  int n = blockIdx.x*256 + threadIdx.x;
  if (n >= NN) return;
  int k0 = blockIdx.y * 16;
  float acc[16];
  #pragma unroll
  for (int t=0;t<16;t++) acc[t] = b1[k0+t];
  for (int tj=0; tj<8; tj++){
    const float* hr = h1t + ((size_t)tj * NN + n) * 16;
    float h[16];
    #pragma unroll
    for (int q=0;q<4;q++){ float4 v = ld4(hr+4*q); h[4*q]=v.x; h[4*q+1]=v.y; h[4*q+2]=v.z; h[4*q+3]=v.w; }
    const float* w = W1 + (size_t)tj*16*ENCD + k0;
    #pragma unroll
    for (int jj=0;jj<16;jj++){
      #pragma unroll
      for (int t=0;t<16;t++) acc[t] = fmaf(h[jj], w[(size_t)jj*ENCD + t], acc[t]);
    }
  }
  float* out = enc + (size_t)n*ENCD + k0;
  #pragma unroll
  for (int q=0;q<4;q++){ float4 v; v.x=acc[4*q]; v.y=acc[4*q+1]; v.z=acc[4*q+2]; v.w=acc[4*q+3]; st4(out+4*q, v); }
}

// h2 = relu(enc @ dW0 + db0), tiled h2t[tile][n][16]
__global__ __launch_bounds__(256) void k_dec1(const float* __restrict__ enc, const float* __restrict__ dW0,
    const float* __restrict__ db0, float* __restrict__ h2t){
  int n = blockIdx.x*256 + threadIdx.x;
  if (n >= NN) return;
  int j0 = blockIdx.y * 16;
  const float* xr = enc + (size_t)n*ENCD;
  float xv[ENCD];
  #pragma unroll
  for (int q=0;q<ENCD/4;q++){ float4 v = ld4(xr + 4*q); xv[4*q]=v.x; xv[4*q+1]=v.y; xv[4*q+2]=v.z; xv[4*q+3]=v.w; }
  float acc[16];
  #pragma unroll
  for (int t=0;t<16;t++) acc[t] = db0[j0+t];
  const float* w = dW0 + j0;
  #pragma unroll
  for (int d=0; d<ENCD; d++){
    #pragma unroll
    for (int t=0;t<16;t++) acc[t] = fmaf(xv[d], w[(size_t)d*H0 + t], acc[t]);
  }
  float* out = h2t + ((size_t)blockIdx.y * NN + n) * 16;
  #pragma unroll
  for (int q=0;q<4;q++){
    float4 v; v.x=fmaxf(acc[4*q],0.f); v.y=fmaxf(acc[4*q+1],0.f); v.z=fmaxf(acc[4*q+2],0.f); v.w=fmaxf(acc[4*q+3],0.f);
    st4(out + 4*q, v);
  }
}

// dec = h2 @ dW1 + db1 ; loss += sum((dec - emb)^2) / (NN*DD)
__global__ __launch_bounds__(256) void k_dec2(const float* __restrict__ h2t, const float* __restrict__ dW1,
    const float* __restrict__ db1, const float* __restrict__ ent, const float* __restrict__ usr,
    float* __restrict__ loss_out){
  int n = blockIdx.x*256 + threadIdx.x;
  int k0 = blockIdx.y * 16;
  float part = 0.f;
  if (n < NN){
    float acc[16];
    #pragma unroll
    for (int t=0;t<16;t++) acc[t] = db1[k0+t];
    for (int tj=0; tj<8; tj++){
      const float* hr = h2t + ((size_t)tj * NN + n) * 16;
      float h[16];
      #pragma unroll
      for (int q=0;q<4;q++){ float4 v = ld4(hr+4*q); h[4*q]=v.x; h[4*q+1]=v.y; h[4*q+2]=v.z; h[4*q+3]=v.w; }
      const float* w = dW1 + (size_t)tj*16*DD + k0;
      #pragma unroll
      for (int jj=0;jj<16;jj++){
        #pragma unroll
        for (int t=0;t<16;t++) acc[t] = fmaf(h[jj], w[(size_t)jj*DD + t], acc[t]);
      }
    }
    const float* xr = (n < N_ENT) ? (ent + (size_t)n*DD + k0) : (usr + (size_t)(n-N_ENT)*DD + k0);
    #pragma unroll
    for (int t=0;t<16;t++){ float d_ = acc[t] - xr[t]; part = fmaf(d_, d_, part); }
  }
  #pragma unroll
  for (int off=32; off>0; off>>=1) part += __shfl_down(part, off, 64);
  __shared__ float sred[4];
  if ((threadIdx.x & 63)==0) sred[threadIdx.x>>6] = part;
  __syncthreads();
  if (threadIdx.x==0){
    float s = (sred[0]+sred[1]+sred[2]+sred[3]) * (1.0f/((float)NN*(float)DD));
    atomicAdd(loss_out, s);
  }
}

// 64-bucket histogram of edge destinations
__global__ __launch_bounds__(256) void k_hist64(const int* __restrict__ edst, int* __restrict__ bktCnt, int E_){
  __shared__ int h[NB];
  for (int i=threadIdx.x; i<NB; i+=256) h[i]=0;
  __syncthreads();
  int i0 = blockIdx.x*4096;
  #pragma unroll
  for (int k=0;k<16;k++){
    int e = i0 + k*256 + threadIdx.x;
    if (e < E_) atomicAdd(&h[((unsigned)edst[e])>>BSH], 1);
  }
  __syncthreads();
  for (int i=threadIdx.x; i<NB; i+=256) if (h[i]) atomicAdd(&bktCnt[i], h[i]);
}

// exclusive scan of 64 bucket counts (single wave)
__global__ __launch_bounds__(64) void k_scan64(const int* __restrict__ bktCnt, int* __restrict__ bktBase){
  int t = threadIdx.x;
  int v = bktCnt[t];
  int x = v;
  #pragma unroll
  for (int off=1; off<64; off<<=1){
    int y = __shfl_up(x, off, 64);
    if (t >= off) x += y;
  }
  bktBase[t] = x - v;
}

// bucketed append: each block reserves exclusive contiguous chunks per bucket
__global__ __launch_bounds__(256) void k_bucketA(const int* __restrict__ esrc, const int* __restrict__ edst,
    const int* __restrict__ erel, const int* __restrict__ bktBase, int* __restrict__ bktFill,
    unsigned* __restrict__ bktData, int E_){
  __shared__ int h[NB];
  __shared__ int gbase[NB];
  for (int i=threadIdx.x; i<NB; i+=256) h[i]=0;
  __syncthreads();
  int i0 = blockIdx.x*4096;
  int dcache[16];
  #pragma unroll
  for (int k=0;k<16;k++){
    int e = i0 + k*256 + threadIdx.x;
    int d = (e < E_) ? edst[e] : -1;
    dcache[k] = d;
    if (d >= 0) atomicAdd(&h[((unsigned)d)>>BSH], 1);
  }
  __syncthreads();
  if (threadIdx.x < NB){
    int c = h[threadIdx.x];
    int off = c ? atomicAdd(&bktFill[threadIdx.x], c) : 0;
    gbase[threadIdx.x] = bktBase[threadIdx.x] + off;
    h[threadIdx.x] = 0;   // reuse as local fill
  }
  __syncthreads();
  #pragma unroll
  for (int k=0;k<16;k++){
    int e = i0 + k*256 + threadIdx.x;
    if (e >= E_) continue;
    int d = dcache[k];
    int b = ((unsigned)d) >> BSH;
    int slot = atomicAdd(&h[b], 1);
    unsigned rec = (unsigned)esrc[e] | ((unsigned)erel[e] << 16) | ((unsigned)(d & ((1<<BSH)-1)) << 20);
    bktData[(size_t)gbase[b] + slot] = rec;
  }
}

// per-bucket CSR build: counts+scan in LDS, localized writes
__global__ __launch_bounds__(1024) void k_buildB(const unsigned* __restrict__ bktData,
    const int* __restrict__ bktBase, const int* __restrict__ bktCnt,
    int* __restrict__ rowp, int* __restrict__ packed){
  __shared__ int cnt[1024];
  __shared__ int start[1024];
  __shared__ int wps[16];
  int b = blockIdx.x;
  int base = bktBase[b];
  int n = bktCnt[b];
  int t = threadIdx.x;
  cnt[t] = 0;
  __syncthreads();
  for (int i=t; i<n; i+=1024) atomicAdd(&cnt[bktData[base+i] >> 20], 1);
  __syncthreads();
  int v = cnt[t];
  cnt[t] = 0;                       // reset for fill pass
  int x = v;
  #pragma unroll
  for (int off=1; off<64; off<<=1){
    int y = __shfl_up(x, off, 64);
    if ((t & 63) >= off) x += y;
  }
  if ((t & 63) == 63) wps[t >> 6] = x;
  __syncthreads();
  if (t < 16){
    int wv = wps[t];
    int wx = wv;
    #pragma unroll
    for (int off=1; off<16; off<<=1){
      int y = __shfl_up(wx, off, 16);
      if (t >= off) wx += y;
    }
    wps[t] = wx - wv;               // exclusive wave prefix
  }
  __syncthreads();
  int sv = (x - v) + wps[t >> 6];   // exclusive prefix over dl
  start[t] = sv;
  int node = (b << BSH) + t;
  if (node <= NN) rowp[node] = base + sv;   // node==NN lands in bucket 58 @ t=608 -> rowp[NN]=E
  __syncthreads();
  for (int i=t; i<n; i+=1024){
    unsigned r = bktData[base+i];
    int dl = r >> 20;
    int p = start[dl] + atomicAdd(&cnt[dl], 1);
    packed[base + p] = (int)(r & 0xFFFFF);
  }
}

// Per-node per-relation gate partials + f16 record pack:
// dA[n][r] = x[n].wsum[r][0:32] (f32); rec[n] = [32 f16 x | 16 f16 dB] (96B)
__global__ __launch_bounds__(256) void k_dots(const float* __restrict__ x, const float* __restrict__ wsum,
    float* __restrict__ dA, __half* __restrict__ rec){
  __shared__ float wl[RR*DD];                  // wl[j*16+rel] = wsum[rel*64+j]
  for (int i = threadIdx.x; i < RR*DD; i += 256){
    int r = i & 15; int j = i >> 4;
    wl[i] = wsum[r*DD + j];
  }
  __syncthreads();
  int t = blockIdx.x*256 + threadIdx.x;
  if (t >= NN*RR) return;
  int n = t >> 4, r = t & 15;
  const float* xr = x + (size_t)n*ENCD;
  float a = 0.f, b = 0.f;
  float xlo = 0.f, xhi = 0.f;
  #pragma unroll
  for (int q=0;q<8;q++){
    float4 v = ld4(xr + 4*q);
    int j = 4*q;
    if (r >= j && r < j+4){ float tmp[4]={v.x,v.y,v.z,v.w}; xlo = tmp[r-j]; }
    if (r+16 >= j && r+16 < j+4){ float tmp[4]={v.x,v.y,v.z,v.w}; xhi = tmp[r+16-j]; }
    a = fmaf(v.x, wl[(j+0)*16 + r], a);
    a = fmaf(v.y, wl[(j+1)*16 + r], a);
    a = fmaf(v.z, wl[(j+2)*16 + r], a);
    a = fmaf(v.w, wl[(j+3)*16 + r], a);
    b = fmaf(v.x, wl[(32+j+0)*16 + r], b);
    b = fmaf(v.y, wl[(32+j+1)*16 + r], b);
    b = fmaf(v.z, wl[(32+j+2)*16 + r], b);
    b = fmaf(v.w, wl[(32+j+3)*16 + r], b);
  }
  dA[t] = a;
  __half* rb = rec + (size_t)n*48;
  rb[r]      = __float2half(xlo);
  rb[16 + r] = __float2half(xhi);
  rb[32 + r] = __float2half(b);
}

// Fused gate + scatter-mean via CSR gather: 16 lanes per node, f16 records
__global__ __launch_bounds__(256) void k_agg(const __half2* __restrict__ rec, const int* __restrict__ packed,
    const int* __restrict__ rowp, const float* __restrict__ dA, float* __restrict__ agg){
  int node = blockIdx.x*16 + (threadIdx.x >> 4);
  int l = threadIdx.x & 15;
  if (node >= NN) return;
  float dv = dA[node*16 + l];                  // lane r holds dA[node][r]
  int beg = rowp[node], end = rowp[node+1];
  float ax = 0.f, ay = 0.f;
  #pragma unroll 2
  for (int i = beg; i < end; i++){
    int p = packed[i];
    int s = p & 0xFFFF;
    int r = (p >> 16) & 15;
    const __half2* rb = rec + (size_t)s*24;    // 24 half2 per node (96B)
    __half2 hx = rb[l];                        // x feats {2l, 2l+1}
    __half2 hb = rb[16 + (l & 7)];             // dB pair {2(l&7), 2(l&7)+1}
    int hbi = *reinterpret_cast<int*>(&hb);
    int got = __shfl(hbi, r >> 1, 16);
    __half2 hp = *reinterpret_cast<__half2*>(&got);
    float db = (r & 1) ? __high2float(hp) : __low2float(hp);
    float z = __shfl(dv, r, 16) + db;
    float g = 1.f / (1.f + __expf(-z));
    float2 fx = __half22float2(hx);
    ax = fmaf(fx.x, g, ax);
    ay = fmaf(fx.y, g, ay);
  }
  int deg = end - beg;
  float inv = (deg > 0) ? 1.f/(float)deg : 0.f;
  float2 o; o.x = ax*inv; o.y = ay*inv;
  *reinterpret_cast<float2*>(&agg[(size_t)node*ENCD + 2*l]) = o;
}

// out = leaky_relu(concat(x,agg) @ W + b), W is [64][outd]
__global__ __launch_bounds__(256) void k_lin(const float* __restrict__ x, const float* __restrict__ agg,
    const float* __restrict__ W, const float* __restrict__ b, float* __restrict__ out, int outd){
  int n = blockIdx.x*256 + threadIdx.x;
  if (n >= NN) return;
  int k0 = blockIdx.y * 16;
  const float* xr = x   + (size_t)n*ENCD;
  const float* ar = agg + (size_t)n*ENCD;
  float xv[32], av[32];
  #pragma unroll
  for (int q=0;q<8;q++){ float4 v = ld4(xr+4*q); xv[4*q]=v.x; xv[4*q+1]=v.y; xv[4*q+2]=v.z; xv[4*q+3]=v.w; }
  #pragma unroll
  for (int q=0;q<8;q++){ float4 v = ld4(ar+4*q); av[4*q]=v.x; av[4*q+1]=v.y; av[4*q+2]=v.z; av[4*q+3]=v.w; }
  float acc[16];
  #pragma unroll
  for (int t=0;t<16;t++) acc[t] = b[k0+t];
  #pragma unroll
  for (int j=0;j<32;j++){
    #pragma unroll
    for (int t=0;t<16;t++) acc[t] = fmaf(xv[j], W[(size_t)j*outd + k0 + t], acc[t]);
  }
  #pragma unroll
  for (int j=0;j<32;j++){
    #pragma unroll
    for (int t=0;t<16;t++) acc[t] = fmaf(av[j], W[(size_t)(32+j)*outd + k0 + t], acc[t]);
  }
  float* o = out + (size_t)n*outd + k0;
  #pragma unroll
  for (int q=0;q<4;q++){
    float4 v;
    float a0=acc[4*q],a1=acc[4*q+1],a2=acc[4*q+2],a3=acc[4*q+3];
    v.x = a0>0.f? a0 : 0.01f*a0;
    v.y = a1>0.f? a1 : 0.01f*a1;
    v.z = a2>0.f? a2 : 0.01f*a2;
    v.w = a3>0.f? a3 : 0.01f*a3;
    st4(o + 4*q, v);
  }
}

__global__ __launch_bounds__(256) void k_score(const float* __restrict__ x1, const float* __restrict__ x2,
    const int* __restrict__ users, const int* __restrict__ items, float* __restrict__ out, int Bn){
  int b = blockIdx.x*256 + threadIdx.x;
  if (b >= Bn) return;
  int u  = N_ENT + users[b];
  int it = items[b];
  const float* a1 = x1 + (size_t)u*32;
  const float* c1 = x1 + (size_t)it*32;
  const float* a2 = x2 + (size_t)u*16;
  const float* c2 = x2 + (size_t)it*16;
  float s = 0.f;
  #pragma unroll
  for (int q=0;q<8;q++){
    float4 va=ld4(a1+4*q), vb=ld4(c1+4*q);
    s = fmaf(va.x,vb.x,s); s = fmaf(va.y,vb.y,s); s = fmaf(va.z,vb.z,s); s = fmaf(va.w,vb.w,s);
  }
  #pragma unroll
  for (int q=0;q<4;q++){
    float4 va=ld4(a2+4*q), vb=ld4(c2+4*q);
    s = fmaf(va.x,vb.x,s); s = fmaf(va.y,vb.y,s); s = fmaf(va.z,vb.z,s); s = fmaf(va.w,vb.w,s);
  }
  out[b] = s;
}

extern "C" void kernel_launch(void* const* d_in, const int* in_sizes, int n_in,
                              void* d_out, int out_size, void* d_ws, size_t ws_size,
                              hipStream_t stream){
  const int*   users   = (const int*)d_in[0];
  const int*   items   = (const int*)d_in[1];
  const int*   esrc    = (const int*)d_in[2];
  const int*   edst    = (const int*)d_in[3];
  const int*   erel    = (const int*)d_in[4];
  const float* ent     = (const float*)d_in[5];
  const float* usr     = (const float*)d_in[6];
  const float* enc_W0  = (const float*)d_in[7];
  const float* enc_b0  = (const float*)d_in[8];
  const float* enc_W1  = (const float*)d_in[9];
  const float* enc_b1  = (const float*)d_in[10];
  const float* dec_W0  = (const float*)d_in[11];
  const float* dec_b0  = (const float*)d_in[12];
  const float* dec_W1  = (const float*)d_in[13];
  const float* dec_b1  = (const float*)d_in[14];
  const float* Wr1     = (const float*)d_in[15];
  const float* lin_W1  = (const float*)d_in[16];
  const float* lin_b1  = (const float*)d_in[17];
  const float* Wr2     = (const float*)d_in[18];
  const float* lin_W2  = (const float*)d_in[19];
  const float* lin_b2  = (const float*)d_in[20];
  const int E = in_sizes[2];
  const int B = in_sizes[0];

  char* wp = (char*)d_ws;
  auto carve = [&](size_t bytes)->char*{ char* p = wp; wp += (bytes + 255) & ~(size_t)255; return p; };
  float* enc    = (float*)carve((size_t)NN*32*4);
  float* x1     = (float*)carve((size_t)NN*32*4);
  float* x2     = (float*)carve((size_t)NN*16*4);
  float* agg    = (float*)carve((size_t)NN*32*4);
  float* h1t    = (float*)carve((size_t)NN*128*4);   // reused: h2t, then bktData
  float* wsum   = (float*)carve((size_t)2*RR*DD*4);
  float* dA     = (float*)carve((size_t)NN*RR*4);
  __half* rec   = (__half*)carve((size_t)NN*48*2);   // 96B/node: [32 f16 x | 16 f16 dB]
  int*   packed = (int*)  carve((size_t)E*4);
  int*   bktCnt = (int*)  carve(128*4);              // bktCnt[64] + bktFill[64], one memset
  int*   bktFill= bktCnt + NB;
  int*   bktBase= (int*)  carve(NB*4);
  int*   rowp   = (int*)  carve(((size_t)NN+1)*4);
  unsigned* bktData = (unsigned*)h1t;                // alias: used only after dec path done

  const int nbN = (NN + 255)/256;   // 235
  const int nbT = (E + 4095)/4096;  // 4096-edge tiles
  const int nbD = (NN*RR + 255)/256;
  dim3 blk(256);

  hipMemsetAsync(d_out, 0, (size_t)out_size*sizeof(float), stream);
  hipMemsetAsync(bktCnt, 0, 128*sizeof(int), stream);

  k_wsum <<<dim3((2*RR*DD+255)/256), blk, 0, stream>>>(Wr1, Wr2, wsum);
  k_enc1 <<<dim3(nbN, 8), blk, 0, stream>>>(ent, usr, enc_W0, enc_b0, h1t);
  k_enc2 <<<dim3(nbN, 2), blk, 0, stream>>>(h1t, enc_W1, enc_b1, enc);
  k_dec1 <<<dim3(nbN, 8), blk, 0, stream>>>(enc, dec_W0, dec_b0, h1t);
  k_dec2 <<<dim3(nbN, 4), blk, 0, stream>>>(h1t, dec_W1, dec_b1, ent, usr, ((float*)d_out) + B);

  // CSR build via 64-bucket two-phase counting sort (h1t dead now; bktData aliases it)
  k_hist64 <<<nbT, blk, 0, stream>>>(edst, bktCnt, E);
  k_scan64 <<<1, dim3(64), 0, stream>>>(bktCnt, bktBase);
  k_bucketA<<<nbT, blk, 0, stream>>>(esrc, edst, erel, bktBase, bktFill, bktData, E);
  k_buildB <<<NB, dim3(1024), 0, stream>>>(bktData, bktBase, bktCnt, rowp, packed);

  k_dots <<<nbD, blk, 0, stream>>>(enc, wsum, dA, rec);
  k_agg  <<<(NN+15)/16, blk, 0, stream>>>((const __half2*)rec, packed, rowp, dA, agg);
  k_lin  <<<dim3(nbN, 2), blk, 0, stream>>>(enc, agg, lin_W1, lin_b1, x1, 32);

  k_dots <<<nbD, blk, 0, stream>>>(x1, wsum + RR*DD, dA, rec);
  k_agg  <<<(NN+15)/16, blk, 0, stream>>>((const __half2*)rec, packed, rowp, dA, agg);
  k_lin  <<<dim3(nbN, 1), blk, 0, stream>>>(x1, agg, lin_W2, lin_b2, x2, 16);

  k_score<<<(B+255)/256, blk, 0, stream>>>(x1, x2, users, items, (float*)d_out, B);
}

// Round 6
// 443.259 us; speedup vs baseline: 1.8230x; 1.0955x over previous
//
#include <hip/hip_runtime.h>
#include <hip/hip_fp16.h>
#include <math.h>

#define N_ENT 50000
#define N_USR 10000
#define NN    60000
#define DD    64
#define H0    128
#define ENCD  32
#define RR    16
#define NB    256
#define BSH   8
#define NBU   235   // ceil(NN/256): buckets actually used

__device__ __forceinline__ float4 ld4(const float* p){ return *reinterpret_cast<const float4*>(p); }
__device__ __forceinline__ void st4(float* p, float4 v){ *reinterpret_cast<float4*>(p) = v; }

// w_sum[layer][r*64+j] = sum_k Wr[r][j][k]
__global__ __launch_bounds__(256) void k_wsum(const float* __restrict__ Wr1, const float* __restrict__ Wr2,
                                              float* __restrict__ wsum){
  int i = blockIdx.x*256 + threadIdx.x;        // 0..2047
  if (i >= 2*RR*DD) return;
  const float* Wr = (i < RR*DD) ? Wr1 : Wr2;
  int loc = i & (RR*DD - 1);                   // r*64+j
  const float* p = Wr + (size_t)loc*32;
  float s = 0.f;
  #pragma unroll
  for (int k=0;k<32;k++) s += p[k];
  wsum[i] = s;
}

// h1 = relu(emb @ W0 + b0), stored tiled: h1t[tile][n][16]
__global__ __launch_bounds__(256) void k_enc1(const float* __restrict__ ent, const float* __restrict__ usr,
    const float* __restrict__ W0, const float* __restrict__ b0, float* __restrict__ h1t){
  int n = blockIdx.x*256 + threadIdx.x;
  if (n >= NN) return;
  int j0 = blockIdx.y * 16;
  const float* xr = (n < N_ENT) ? (ent + (size_t)n*DD) : (usr + (size_t)(n-N_ENT)*DD);
  float xv[DD];
  #pragma unroll
  for (int q=0;q<DD/4;q++){ float4 v = ld4(xr + 4*q); xv[4*q]=v.x; xv[4*q+1]=v.y; xv[4*q+2]=v.z; xv[4*q+3]=v.w; }
  float acc[16];
  #pragma unroll
  for (int t=0;t<16;t++) acc[t] = b0[j0+t];
  const float* w = W0 + j0;
  #pragma unroll
  for (int d=0; d<DD; d++){
    #pragma unroll
    for (int t=0;t<16;t++) acc[t] = fmaf(xv[d], w[(size_t)d*H0 + t], acc[t]);
  }
  float* out = h1t + ((size_t)blockIdx.y * NN + n) * 16;
  #pragma unroll
  for (int q=0;q<4;q++){
    float4 v; v.x=fmaxf(acc[4*q],0.f); v.y=fmaxf(acc[4*q+1],0.f); v.z=fmaxf(acc[4*q+2],0.f); v.w=fmaxf(acc[4*q+3],0.f);
    st4(out + 4*q, v);
  }
}

// enc = h1 @ W1 + b1  (single pass: each thread computes all 32 outputs)
__global__ __launch_bounds__(256) void k_enc2(const float* __restrict__ h1t, const float* __restrict__ W1,
    const float* __restrict__ b1, float* __restrict__ enc){
  int n = blockIdx.x*256 + threadIdx.x;
  if (n >= NN) return;
  float acc[32];
  #pragma unroll
  for (int t=0;t<32;t++) acc[t] = b1[t];
  for (int tj=0; tj<8; tj++){
    const float* hr = h1t + ((size_t)tj * NN + n) * 16;
    float h[16];
    #pragma unroll
    for (int q=0;q<4;q++){ float4 v = ld4(hr+4*q); h[4*q]=v.x; h[4*q+1]=v.y; h[4*q+2]=v.z; h[4*q+3]=v.w; }
    const float* w = W1 + (size_t)tj*16*ENCD;
    #pragma unroll
    for (int jj=0;jj<16;jj++){
      #pragma unroll
      for (int t=0;t<32;t++) acc[t] = fmaf(h[jj], w[(size_t)jj*ENCD + t], acc[t]);
    }
  }
  float* out = enc + (size_t)n*ENCD;
  #pragma unroll
  for (int q=0;q<8;q++){ float4 v; v.x=acc[4*q]; v.y=acc[4*q+1]; v.z=acc[4*q+2]; v.w=acc[4*q+3]; st4(out+4*q, v); }
}

// h2 = relu(enc @ dW0 + db0), tiled h2t[tile][n][16]
__global__ __launch_bounds__(256) void k_dec1(const float* __restrict__ enc, const float* __restrict__ dW0,
    const float* __restrict__ db0, float* __restrict__ h2t){
  int n = blockIdx.x*256 + threadIdx.x;
  if (n >= NN) return;
  int j0 = blockIdx.y * 16;
  const float* xr = enc + (size_t)n*ENCD;
  float xv[ENCD];
  #pragma unroll
  for (int q=0;q<ENCD/4;q++){ float4 v = ld4(xr + 4*q); xv[4*q]=v.x; xv[4*q+1]=v.y; xv[4*q+2]=v.z; xv[4*q+3]=v.w; }
  float acc[16];
  #pragma unroll
  for (int t=0;t<16;t++) acc[t] = db0[j0+t];
  const float* w = dW0 + j0;
  #pragma unroll
  for (int d=0; d<ENCD; d++){
    #pragma unroll
    for (int t=0;t<16;t++) acc[t] = fmaf(xv[d], w[(size_t)d*H0 + t], acc[t]);
  }
  float* out = h2t + ((size_t)blockIdx.y * NN + n) * 16;
  #pragma unroll
  for (int q=0;q<4;q++){
    float4 v; v.x=fmaxf(acc[4*q],0.f); v.y=fmaxf(acc[4*q+1],0.f); v.z=fmaxf(acc[4*q+2],0.f); v.w=fmaxf(acc[4*q+3],0.f);
    st4(out + 4*q, v);
  }
}

// dec = h2 @ dW1 + db1 ; loss += sum((dec - emb)^2) / (NN*DD); 32-wide output tiles
__global__ __launch_bounds__(256) void k_dec2(const float* __restrict__ h2t, const float* __restrict__ dW1,
    const float* __restrict__ db1, const float* __restrict__ ent, const float* __restrict__ usr,
    float* __restrict__ loss_out){
  int n = blockIdx.x*256 + threadIdx.x;
  int k0 = blockIdx.y * 32;
  float part = 0.f;
  if (n < NN){
    float acc[32];
    #pragma unroll
    for (int t=0;t<32;t++) acc[t] = db1[k0+t];
    for (int tj=0; tj<8; tj++){
      const float* hr = h2t + ((size_t)tj * NN + n) * 16;
      float h[16];
      #pragma unroll
      for (int q=0;q<4;q++){ float4 v = ld4(hr+4*q); h[4*q]=v.x; h[4*q+1]=v.y; h[4*q+2]=v.z; h[4*q+3]=v.w; }
      const float* w = dW1 + (size_t)tj*16*DD + k0;
      #pragma unroll
      for (int jj=0;jj<16;jj++){
        #pragma unroll
        for (int t=0;t<32;t++) acc[t] = fmaf(h[jj], w[(size_t)jj*DD + t], acc[t]);
      }
    }
    const float* xr = (n < N_ENT) ? (ent + (size_t)n*DD + k0) : (usr + (size_t)(n-N_ENT)*DD + k0);
    #pragma unroll
    for (int t=0;t<32;t++){ float d_ = acc[t] - xr[t]; part = fmaf(d_, d_, part); }
  }
  #pragma unroll
  for (int off=32; off>0; off>>=1) part += __shfl_down(part, off, 64);
  __shared__ float sred[4];
  if ((threadIdx.x & 63)==0) sred[threadIdx.x>>6] = part;
  __syncthreads();
  if (threadIdx.x==0){
    float s = (sred[0]+sred[1]+sred[2]+sred[3]) * (1.0f/((float)NN*(float)DD));
    atomicAdd(loss_out, s);
  }
}

// 256-bucket histogram of edge destinations
__global__ __launch_bounds__(256) void k_hist256(const int* __restrict__ edst, int* __restrict__ bktCnt, int E_){
  __shared__ int h[NB];
  h[threadIdx.x]=0;
  __syncthreads();
  int i0 = blockIdx.x*4096;
  #pragma unroll
  for (int k=0;k<16;k++){
    int e = i0 + k*256 + threadIdx.x;
    if (e < E_) atomicAdd(&h[((unsigned)edst[e])>>BSH], 1);
  }
  __syncthreads();
  int c = h[threadIdx.x];
  if (c) atomicAdd(&bktCnt[threadIdx.x], c);
}

// exclusive scan of 256 bucket counts (one block)
__global__ __launch_bounds__(256) void k_scan256(const int* __restrict__ bktCnt, int* __restrict__ bktBase){
  __shared__ int wps[4];
  int t = threadIdx.x;
  int v = bktCnt[t];
  int x = v;
  #pragma unroll
  for (int off=1; off<64; off<<=1){
    int y = __shfl_up(x, off, 64);
    if ((t & 63) >= off) x += y;
  }
  if ((t & 63) == 63) wps[t >> 6] = x;
  __syncthreads();
  if (t < 4){
    int wv = wps[t];
    int wx = wv;
    #pragma unroll
    for (int off=1; off<4; off<<=1){
      int y = __shfl_up(wx, off, 4);
      if (t >= off) wx += y;
    }
    wps[t] = wx - wv;
  }
  __syncthreads();
  bktBase[t] = (x - v) + wps[t >> 6];
}

// bucketed append: each block reserves exclusive contiguous chunks per bucket
__global__ __launch_bounds__(256) void k_bucketA(const int* __restrict__ esrc, const int* __restrict__ edst,
    const int* __restrict__ erel, const int* __restrict__ bktBase, int* __restrict__ bktFill,
    unsigned* __restrict__ bktData, int E_){
  __shared__ int h[NB];
  __shared__ int gbase[NB];
  h[threadIdx.x]=0;
  __syncthreads();
  int i0 = blockIdx.x*4096;
  int dcache[16];
  #pragma unroll
  for (int k=0;k<16;k++){
    int e = i0 + k*256 + threadIdx.x;
    int d = (e < E_) ? edst[e] : -1;
    dcache[k] = d;
    if (d >= 0) atomicAdd(&h[((unsigned)d)>>BSH], 1);
  }
  __syncthreads();
  {
    int c = h[threadIdx.x];
    int off = c ? atomicAdd(&bktFill[threadIdx.x], c) : 0;
    gbase[threadIdx.x] = bktBase[threadIdx.x] + off;
    h[threadIdx.x] = 0;   // reuse as local fill
  }
  __syncthreads();
  #pragma unroll
  for (int k=0;k<16;k++){
    int e = i0 + k*256 + threadIdx.x;
    if (e >= E_) continue;
    int d = dcache[k];
    int b = ((unsigned)d) >> BSH;
    int slot = atomicAdd(&h[b], 1);
    unsigned rec = (unsigned)esrc[e] | ((unsigned)erel[e] << 16) | ((unsigned)(d & 0xFF) << 20);
    bktData[(size_t)gbase[b] + slot] = rec;
  }
}

// per-bucket CSR build: counts+scan in LDS, localized writes; keeps dl bits in packed
__global__ __launch_bounds__(256) void k_buildB(const unsigned* __restrict__ bktData,
    const int* __restrict__ bktBase, const int* __restrict__ bktCnt,
    int* __restrict__ rowp, int* __restrict__ packed){
  __shared__ int cnt[NB];
  __shared__ int start[NB];
  __shared__ int wps[4];
  int b = blockIdx.x;
  int base = bktBase[b];
  int n = bktCnt[b];
  int t = threadIdx.x;
  cnt[t] = 0;
  __syncthreads();
  for (int i=t; i<n; i+=256) atomicAdd(&cnt[(bktData[base+i] >> 20) & 0xFF], 1);
  __syncthreads();
  int v = cnt[t];
  cnt[t] = 0;                       // reset for fill pass
  int x = v;
  #pragma unroll
  for (int off=1; off<64; off<<=1){
    int y = __shfl_up(x, off, 64);
    if ((t & 63) >= off) x += y;
  }
  if ((t & 63) == 63) wps[t >> 6] = x;
  __syncthreads();
  if (t < 4){
    int wv = wps[t];
    int wx = wv;
    #pragma unroll
    for (int off=1; off<4; off<<=1){
      int y = __shfl_up(wx, off, 4);
      if (t >= off) wx += y;
    }
    wps[t] = wx - wv;
  }
  __syncthreads();
  int sv = (x - v) + wps[t >> 6];   // exclusive prefix over dl
  start[t] = sv;
  int node = (b << BSH) + t;
  if (node <= NN) rowp[node] = base + sv;
  __syncthreads();
  for (int i=t; i<n; i+=256){
    unsigned r = bktData[base+i];
    int dl = (r >> 20) & 0xFF;
    int p = start[dl] + atomicAdd(&cnt[dl], 1);
    packed[base + p] = (int)r;      // keep src|rel|dl
  }
}

// Per-node per-relation gate partials + f16 tables:
// dA[n][r] (f32, dst side), dbrec[n][r] (f16, src side), xrec[n][0:32] (f16 features)
__global__ __launch_bounds__(256) void k_dots(const float* __restrict__ x, const float* __restrict__ wsum,
    float* __restrict__ dA, __half* __restrict__ dbrec, __half* __restrict__ xrec){
  __shared__ float wl[RR*DD];                  // wl[j*16+rel] = wsum[rel*64+j]
  for (int i = threadIdx.x; i < RR*DD; i += 256){
    int r = i & 15; int j = i >> 4;
    wl[i] = wsum[r*DD + j];
  }
  __syncthreads();
  int t = blockIdx.x*256 + threadIdx.x;
  if (t >= NN*RR) return;
  int n = t >> 4, r = t & 15;
  const float* xr = x + (size_t)n*ENCD;
  float a = 0.f, b = 0.f;
  float xlo = 0.f, xhi = 0.f;
  #pragma unroll
  for (int q=0;q<8;q++){
    float4 v = ld4(xr + 4*q);
    int j = 4*q;
    if (r >= j && r < j+4){ float tmp[4]={v.x,v.y,v.z,v.w}; xlo = tmp[r-j]; }
    if (r+16 >= j && r+16 < j+4){ float tmp[4]={v.x,v.y,v.z,v.w}; xhi = tmp[r+16-j]; }
    a = fmaf(v.x, wl[(j+0)*16 + r], a);
    a = fmaf(v.y, wl[(j+1)*16 + r], a);
    a = fmaf(v.z, wl[(j+2)*16 + r], a);
    a = fmaf(v.w, wl[(j+3)*16 + r], a);
    b = fmaf(v.x, wl[(32+j+0)*16 + r], b);
    b = fmaf(v.y, wl[(32+j+1)*16 + r], b);
    b = fmaf(v.z, wl[(32+j+2)*16 + r], b);
    b = fmaf(v.w, wl[(32+j+3)*16 + r], b);
  }
  dA[t] = a;
  dbrec[t] = __float2half(b);
  xrec[(size_t)n*32 + r]      = __float2half(xlo);
  xrec[(size_t)n*32 + 16 + r] = __float2half(xhi);
}

// Per-edge gate pass: sequential packed stream, L2-resident dbrec gather, f16 gate stream out
__global__ __launch_bounds__(256) void k_gates(const int* __restrict__ packed,
    const int* __restrict__ bktBase, const int* __restrict__ bktCnt,
    const float* __restrict__ dA, const __half* __restrict__ dbrec, __half* __restrict__ gat){
  int b = blockIdx.x >> 2, g = blockIdx.x & 3;
  int base = bktBase[b], n = bktCnt[b];
  int lo = (n*g) >> 2, hi = (n*(g+1)) >> 2;
  for (int i = lo + (int)threadIdx.x; i < hi; i += 256){
    int p = packed[base+i];
    int s = p & 0xFFFF;
    int r = (p >> 16) & 15;
    int dl = (p >> 20) & 0xFF;
    int dst = (b << BSH) | dl;
    float z = dA[dst*16 + r] + __half2float(dbrec[s*16 + r]);
    gat[base+i] = __float2half(1.f/(1.f + __expf(-z)));
  }
}

// Scatter-mean via CSR gather: 16 lanes per node, only xrec (L2-resident) gathered
__global__ __launch_bounds__(256) void k_agg(const __half2* __restrict__ xrec2, const int* __restrict__ packed,
    const __half* __restrict__ gat, const int* __restrict__ rowp, float* __restrict__ agg){
  int node = blockIdx.x*16 + (threadIdx.x >> 4);
  int l = threadIdx.x & 15;
  if (node >= NN) return;
  int beg = rowp[node], end = rowp[node+1];
  float ax = 0.f, ay = 0.f;
  #pragma unroll 4
  for (int i = beg; i < end; i++){
    int p = packed[i];
    int s = p & 0xFFFF;
    float g = __half2float(gat[i]);
    float2 fx = __half22float2(xrec2[(size_t)s*16 + l]);
    ax = fmaf(fx.x, g, ax);
    ay = fmaf(fx.y, g, ay);
  }
  int deg = end - beg;
  float inv = (deg > 0) ? 1.f/(float)deg : 0.f;
  float2 o; o.x = ax*inv; o.y = ay*inv;
  *reinterpret_cast<float2*>(&agg[(size_t)node*ENCD + 2*l]) = o;
}

// out = leaky_relu(concat(x,agg) @ W + b), W is [64][outd]
__global__ __launch_bounds__(256) void k_lin(const float* __restrict__ x, const float* __restrict__ agg,
    const float* __restrict__ W, const float* __restrict__ b, float* __restrict__ out, int outd){
  int n = blockIdx.x*256 + threadIdx.x;
  if (n >= NN) return;
  int k0 = blockIdx.y * 16;
  const float* xr = x   + (size_t)n*ENCD;
  const float* ar = agg + (size_t)n*ENCD;
  float xv[32], av[32];
  #pragma unroll
  for (int q=0;q<8;q++){ float4 v = ld4(xr+4*q); xv[4*q]=v.x; xv[4*q+1]=v.y; xv[4*q+2]=v.z; xv[4*q+3]=v.w; }
  #pragma unroll
  for (int q=0;q<8;q++){ float4 v = ld4(ar+4*q); av[4*q]=v.x; av[4*q+1]=v.y; av[4*q+2]=v.z; av[4*q+3]=v.w; }
  float acc[16];
  #pragma unroll
  for (int t=0;t<16;t++) acc[t] = b[k0+t];
  #pragma unroll
  for (int j=0;j<32;j++){
    #pragma unroll
    for (int t=0;t<16;t++) acc[t] = fmaf(xv[j], W[(size_t)j*outd + k0 + t], acc[t]);
  }
  #pragma unroll
  for (int j=0;j<32;j++){
    #pragma unroll
    for (int t=0;t<16;t++) acc[t] = fmaf(av[j], W[(size_t)(32+j)*outd + k0 + t], acc[t]);
  }
  float* o = out + (size_t)n*outd + k0;
  #pragma unroll
  for (int q=0;q<4;q++){
    float4 v;
    float a0=acc[4*q],a1=acc[4*q+1],a2=acc[4*q+2],a3=acc[4*q+3];
    v.x = a0>0.f? a0 : 0.01f*a0;
    v.y = a1>0.f? a1 : 0.01f*a1;
    v.z = a2>0.f? a2 : 0.01f*a2;
    v.w = a3>0.f? a3 : 0.01f*a3;
    st4(o + 4*q, v);
  }
}

__global__ __launch_bounds__(256) void k_score(const float* __restrict__ x1, const float* __restrict__ x2,
    const int* __restrict__ users, const int* __restrict__ items, float* __restrict__ out, int Bn){
  int b = blockIdx.x*256 + threadIdx.x;
  if (b >= Bn) return;
  int u  = N_ENT + users[b];
  int it = items[b];
  const float* a1 = x1 + (size_t)u*32;
  const float* c1 = x1 + (size_t)it*32;
  const float* a2 = x2 + (size_t)u*16;
  const float* c2 = x2 + (size_t)it*16;
  float s = 0.f;
  #pragma unroll
  for (int q=0;q<8;q++){
    float4 va=ld4(a1+4*q), vb=ld4(c1+4*q);
    s = fmaf(va.x,vb.x,s); s = fmaf(va.y,vb.y,s); s = fmaf(va.z,vb.z,s); s = fmaf(va.w,vb.w,s);
  }
  #pragma unroll
  for (int q=0;q<4;q++){
    float4 va=ld4(a2+4*q), vb=ld4(c2+4*q);
    s = fmaf(va.x,vb.x,s); s = fmaf(va.y,vb.y,s); s = fmaf(va.z,vb.z,s); s = fmaf(va.w,vb.w,s);
  }
  out[b] = s;
}

extern "C" void kernel_launch(void* const* d_in, const int* in_sizes, int n_in,
                              void* d_out, int out_size, void* d_ws, size_t ws_size,
                              hipStream_t stream){
  const int*   users   = (const int*)d_in[0];
  const int*   items   = (const int*)d_in[1];
  const int*   esrc    = (const int*)d_in[2];
  const int*   edst    = (const int*)d_in[3];
  const int*   erel    = (const int*)d_in[4];
  const float* ent     = (const float*)d_in[5];
  const float* usr     = (const float*)d_in[6];
  const float* enc_W0  = (const float*)d_in[7];
  const float* enc_b0  = (const float*)d_in[8];
  const float* enc_W1  = (const float*)d_in[9];
  const float* enc_b1  = (const float*)d_in[10];
  const float* dec_W0  = (const float*)d_in[11];
  const float* dec_b0  = (const float*)d_in[12];
  const float* dec_W1  = (const float*)d_in[13];
  const float* dec_b1  = (const float*)d_in[14];
  const float* Wr1     = (const float*)d_in[15];
  const float* lin_W1  = (const float*)d_in[16];
  const float* lin_b1  = (const float*)d_in[17];
  const float* Wr2     = (const float*)d_in[18];
  const float* lin_W2  = (const float*)d_in[19];
  const float* lin_b2  = (const float*)d_in[20];
  const int E = in_sizes[2];
  const int B = in_sizes[0];

  char* wp = (char*)d_ws;
  auto carve = [&](size_t bytes)->char*{ char* p = wp; wp += (bytes + 255) & ~(size_t)255; return p; };
  float* enc    = (float*)carve((size_t)NN*32*4);
  float* x1     = (float*)carve((size_t)NN*32*4);
  float* x2     = (float*)carve((size_t)NN*16*4);
  float* agg    = (float*)carve((size_t)NN*32*4);
  float* h1t    = (float*)carve((size_t)NN*128*4);   // reused: h2t, then bktData
  float* wsum   = (float*)carve((size_t)2*RR*DD*4);
  float* dA     = (float*)carve((size_t)NN*RR*4);
  __half* dbrec = (__half*)carve((size_t)NN*RR*2);   // 32B/node src-side gate dots
  __half* xrec  = (__half*)carve((size_t)NN*32*2);   // 64B/node f16 features
  __half* gat   = (__half*)carve((size_t)E*2);       // per-edge gate stream
  int*   packed = (int*)  carve((size_t)E*4);
  int*   bktCnt = (int*)  carve((size_t)2*NB*4);     // cnt[256] + fill[256], one memset
  int*   bktFill= bktCnt + NB;
  int*   bktBase= (int*)  carve(NB*4);
  int*   rowp   = (int*)  carve(((size_t)NN+1)*4);
  unsigned* bktData = (unsigned*)h1t;                // alias: used only after dec path done

  const int nbN = (NN + 255)/256;   // 235
  const int nbT = (E + 4095)/4096;  // 4096-edge tiles
  const int nbD = (NN*RR + 255)/256;
  dim3 blk(256);

  hipMemsetAsync(d_out, 0, (size_t)out_size*sizeof(float), stream);
  hipMemsetAsync(bktCnt, 0, (size_t)2*NB*sizeof(int), stream);

  k_wsum <<<dim3((2*RR*DD+255)/256), blk, 0, stream>>>(Wr1, Wr2, wsum);
  k_enc1 <<<dim3(nbN, 8), blk, 0, stream>>>(ent, usr, enc_W0, enc_b0, h1t);
  k_enc2 <<<dim3(nbN), blk, 0, stream>>>(h1t, enc_W1, enc_b1, enc);
  k_dec1 <<<dim3(nbN, 8), blk, 0, stream>>>(enc, dec_W0, dec_b0, h1t);
  k_dec2 <<<dim3(nbN, 2), blk, 0, stream>>>(h1t, dec_W1, dec_b1, ent, usr, ((float*)d_out) + B);

  // CSR build via 256-bucket two-phase counting sort (h1t dead now; bktData aliases it)
  k_hist256<<<nbT, blk, 0, stream>>>(edst, bktCnt, E);
  k_scan256<<<1, blk, 0, stream>>>(bktCnt, bktBase);
  k_bucketA<<<nbT, blk, 0, stream>>>(esrc, edst, erel, bktBase, bktFill, bktData, E);
  k_buildB <<<NBU, blk, 0, stream>>>(bktData, bktBase, bktCnt, rowp, packed);

  k_dots <<<nbD, blk, 0, stream>>>(enc, wsum, dA, dbrec, xrec);
  k_gates<<<NBU*4, blk, 0, stream>>>(packed, bktBase, bktCnt, dA, dbrec, gat);
  k_agg  <<<(NN+15)/16, blk, 0, stream>>>((const __half2*)xrec, packed, gat, rowp, agg);
  k_lin  <<<dim3(nbN, 2), blk, 0, stream>>>(enc, agg, lin_W1, lin_b1, x1, 32);

  k_dots <<<nbD, blk, 0, stream>>>(x1, wsum + RR*DD, dA, dbrec, xrec);
  k_gates<<<NBU*4, blk, 0, stream>>>(packed, bktBase, bktCnt, dA, dbrec, gat);
  k_agg  <<<(NN+15)/16, blk, 0, stream>>>((const __half2*)xrec, packed, gat, rowp, agg);
  k_lin  <<<dim3(nbN, 1), blk, 0, stream>>>(x1, agg, lin_W2, lin_b2, x2, 16);

  k_score<<<(B+255)/256, blk, 0, stream>>>(x1, x2, users, items, (float*)d_out, B);
}

// Round 7
// 393.512 us; speedup vs baseline: 2.0534x; 1.1264x over previous
//
#include <hip/hip_runtime.h>
#include <hip/hip_fp16.h>
#include <math.h>

#define N_ENT 50000
#define N_USR 10000
#define NN    60000
#define DD    64
#define H0    128
#define ENCD  32
#define RR    16
#define NB    256
#define BSH   8
#define NBU   235   // ceil(NN/256): buckets actually used

__device__ __forceinline__ float4 ld4(const float* p){ return *reinterpret_cast<const float4*>(p); }
__device__ __forceinline__ void st4(float* p, float4 v){ *reinterpret_cast<float4*>(p) = v; }

// w_sum[layer][r*64+j] = sum_k Wr[r][j][k]
__global__ __launch_bounds__(256) void k_wsum(const float* __restrict__ Wr1, const float* __restrict__ Wr2,
                                              float* __restrict__ wsum){
  int i = blockIdx.x*256 + threadIdx.x;        // 0..2047
  if (i >= 2*RR*DD) return;
  const float* Wr = (i < RR*DD) ? Wr1 : Wr2;
  int loc = i & (RR*DD - 1);                   // r*64+j
  const float* p = Wr + (size_t)loc*32;
  float s = 0.f;
  #pragma unroll
  for (int k=0;k<32;k++) s += p[k];
  wsum[i] = s;
}

// Fully fused autoencoder: x -> h1 -> enc -> h2 -> dec -> loss, one block = 64 nodes.
// LDS tiles stored [feature][node] with stride 65 (conflict-free writes & reads).
// Per-phase output tile is wave-uniform (readfirstlane) so weights come via s_load.
__global__ __launch_bounds__(256) void k_ae(const float* __restrict__ ent, const float* __restrict__ usr,
    const float* __restrict__ eW0, const float* __restrict__ eb0,
    const float* __restrict__ eW1, const float* __restrict__ eb1,
    const float* __restrict__ dW0c, const float* __restrict__ db0,
    const float* __restrict__ dW1c, const float* __restrict__ db1,
    float* __restrict__ enc, float* __restrict__ loss_out){
  __shared__ float xs[DD][65];     // 16.6 KB
  __shared__ float hs[H0][65];     // 33.3 KB  (h1, then h2)
  __shared__ float es[ENCD][65];   // 8.3 KB
  __shared__ float sred[4];
  int t = threadIdx.x;
  int nl = t & 63;
  int wid = __builtin_amdgcn_readfirstlane(t >> 6);   // wave-uniform 0..3

  // stage x: thread t loads 16 floats of node (t>>2), cols (t&3)*16..+15, transposed into xs
  {
    int n2 = t >> 2;
    int d0 = (t & 3) * 16;
    int gnode = blockIdx.x*64 + n2;
    if (gnode < NN){
      const float* xr = (gnode < N_ENT) ? ent + (size_t)gnode*DD : usr + (size_t)(gnode-N_ENT)*DD;
      #pragma unroll
      for (int q=0;q<4;q++){
        float4 v = ld4(xr + d0 + 4*q);
        xs[d0+4*q+0][n2]=v.x; xs[d0+4*q+1][n2]=v.y; xs[d0+4*q+2][n2]=v.z; xs[d0+4*q+3][n2]=v.w;
      }
    } else {
      #pragma unroll
      for (int q=0;q<16;q++) xs[d0+q][n2]=0.f;
    }
  }
  __syncthreads();

  // phase1: h1[j0..j0+31] = relu(x @ eW0 + eb0)
  {
    int j0 = wid*32;
    float acc[32];
    #pragma unroll
    for (int k=0;k<32;k++) acc[k]=eb0[j0+k];
    #pragma unroll 4
    for (int d=0;d<DD;d++){
      float x = xs[d][nl];
      const float* w = eW0 + (size_t)d*H0 + j0;
      #pragma unroll
      for (int k=0;k<32;k++) acc[k]=fmaf(x,w[k],acc[k]);
    }
    #pragma unroll
    for (int k=0;k<32;k++) hs[j0+k][nl]=fmaxf(acc[k],0.f);
  }
  __syncthreads();

  // phase2: enc[k0..k0+7] = h1 @ eW1 + eb1
  {
    int k0 = wid*8;
    float acc[8];
    #pragma unroll
    for (int k=0;k<8;k++) acc[k]=eb1[k0+k];
    #pragma unroll 4
    for (int j=0;j<H0;j++){
      float hv = hs[j][nl];
      const float* w = eW1 + (size_t)j*ENCD + k0;
      #pragma unroll
      for (int k=0;k<8;k++) acc[k]=fmaf(hv,w[k],acc[k]);
    }
    #pragma unroll
    for (int k=0;k<8;k++) es[k0+k][nl]=acc[k];
  }
  __syncthreads();

  // coalesced enc writeout: lane t stores 32B at enc + blockbase*32 + t*8 floats
  {
    int n2 = t >> 2;
    int k2 = (t & 3) * 8;
    int gnode = blockIdx.x*64 + n2;
    if (gnode < NN){
      float4 a, b;
      a.x=es[k2+0][n2]; a.y=es[k2+1][n2]; a.z=es[k2+2][n2]; a.w=es[k2+3][n2];
      b.x=es[k2+4][n2]; b.y=es[k2+5][n2]; b.z=es[k2+6][n2]; b.w=es[k2+7][n2];
      st4(enc + (size_t)gnode*ENCD + k2, a);
      st4(enc + (size_t)gnode*ENCD + k2 + 4, b);
    }
  }

  // phase3: h2[j0..j0+31] = relu(enc @ dW0 + db0)   (reads es, overwrites hs — safe post-sync)
  {
    int j0 = wid*32;
    float acc[32];
    #pragma unroll
    for (int k=0;k<32;k++) acc[k]=db0[j0+k];
    #pragma unroll 4
    for (int d=0;d<ENCD;d++){
      float x = es[d][nl];
      const float* w = dW0c + (size_t)d*H0 + j0;
      #pragma unroll
      for (int k=0;k<32;k++) acc[k]=fmaf(x,w[k],acc[k]);
    }
    #pragma unroll
    for (int k=0;k<32;k++) hs[j0+k][nl]=fmaxf(acc[k],0.f);
  }
  __syncthreads();

  // phase4: dec[c0..c0+15] = h2 @ dW1 + db1 ; accumulate (dec-x)^2
  float part = 0.f;
  {
    int c0 = wid*16;
    float acc[16];
    #pragma unroll
    for (int k=0;k<16;k++) acc[k]=db1[c0+k];
    #pragma unroll 4
    for (int j=0;j<H0;j++){
      float hv = hs[j][nl];
      const float* w = dW1c + (size_t)j*DD + c0;
      #pragma unroll
      for (int k=0;k<16;k++) acc[k]=fmaf(hv,w[k],acc[k]);
    }
    int gnode = blockIdx.x*64 + nl;
    if (gnode < NN){
      #pragma unroll
      for (int k=0;k<16;k++){ float d_ = acc[k]-xs[c0+k][nl]; part = fmaf(d_,d_,part); }
    }
  }
  #pragma unroll
  for (int off=32; off>0; off>>=1) part += __shfl_down(part, off, 64);
  if ((t&63)==0) sred[t>>6] = part;
  __syncthreads();
  if (t==0) atomicAdd(loss_out, (sred[0]+sred[1]+sred[2]+sred[3]) * (1.0f/((float)NN*(float)DD)));
}

// 256-bucket histogram of edge destinations
__global__ __launch_bounds__(256) void k_hist256(const int* __restrict__ edst, int* __restrict__ bktCnt, int E_){
  __shared__ int h[NB];
  h[threadIdx.x]=0;
  __syncthreads();
  int i0 = blockIdx.x*4096;
  #pragma unroll
  for (int k=0;k<16;k++){
    int e = i0 + k*256 + threadIdx.x;
    if (e < E_) atomicAdd(&h[((unsigned)edst[e])>>BSH], 1);
  }
  __syncthreads();
  int c = h[threadIdx.x];
  if (c) atomicAdd(&bktCnt[threadIdx.x], c);
}

// exclusive scan of 256 bucket counts (one block)
__global__ __launch_bounds__(256) void k_scan256(const int* __restrict__ bktCnt, int* __restrict__ bktBase){
  __shared__ int wps[4];
  int t = threadIdx.x;
  int v = bktCnt[t];
  int x = v;
  #pragma unroll
  for (int off=1; off<64; off<<=1){
    int y = __shfl_up(x, off, 64);
    if ((t & 63) >= off) x += y;
  }
  if ((t & 63) == 63) wps[t >> 6] = x;
  __syncthreads();
  if (t < 4){
    int wv = wps[t];
    int wx = wv;
    #pragma unroll
    for (int off=1; off<4; off<<=1){
      int y = __shfl_up(wx, off, 4);
      if (t >= off) wx += y;
    }
    wps[t] = wx - wv;
  }
  __syncthreads();
  bktBase[t] = (x - v) + wps[t >> 6];
}

// bucketed append: each block reserves exclusive contiguous chunks per bucket
__global__ __launch_bounds__(256) void k_bucketA(const int* __restrict__ esrc, const int* __restrict__ edst,
    const int* __restrict__ erel, const int* __restrict__ bktBase, int* __restrict__ bktFill,
    unsigned* __restrict__ bktData, int E_){
  __shared__ int h[NB];
  __shared__ int gbase[NB];
  h[threadIdx.x]=0;
  __syncthreads();
  int i0 = blockIdx.x*4096;
  int dcache[16];
  #pragma unroll
  for (int k=0;k<16;k++){
    int e = i0 + k*256 + threadIdx.x;
    int d = (e < E_) ? edst[e] : -1;
    dcache[k] = d;
    if (d >= 0) atomicAdd(&h[((unsigned)d)>>BSH], 1);
  }
  __syncthreads();
  {
    int c = h[threadIdx.x];
    int off = c ? atomicAdd(&bktFill[threadIdx.x], c) : 0;
    gbase[threadIdx.x] = bktBase[threadIdx.x] + off;
    h[threadIdx.x] = 0;   // reuse as local fill
  }
  __syncthreads();
  #pragma unroll
  for (int k=0;k<16;k++){
    int e = i0 + k*256 + threadIdx.x;
    if (e >= E_) continue;
    int d = dcache[k];
    int b = ((unsigned)d) >> BSH;
    int slot = atomicAdd(&h[b], 1);
    unsigned rec = (unsigned)esrc[e] | ((unsigned)erel[e] << 16) | ((unsigned)(d & 0xFF) << 20);
    bktData[(size_t)gbase[b] + slot] = rec;
  }
}

// per-bucket CSR build: counts+scan in LDS, localized writes; keeps dl bits in packed
__global__ __launch_bounds__(256) void k_buildB(const unsigned* __restrict__ bktData,
    const int* __restrict__ bktBase, const int* __restrict__ bktCnt,
    int* __restrict__ rowp, int* __restrict__ packed){
  __shared__ int cnt[NB];
  __shared__ int start[NB];
  __shared__ int wps[4];
  int b = blockIdx.x;
  int base = bktBase[b];
  int n = bktCnt[b];
  int t = threadIdx.x;
  cnt[t] = 0;
  __syncthreads();
  for (int i=t; i<n; i+=256) atomicAdd(&cnt[(bktData[base+i] >> 20) & 0xFF], 1);
  __syncthreads();
  int v = cnt[t];
  cnt[t] = 0;                       // reset for fill pass
  int x = v;
  #pragma unroll
  for (int off=1; off<64; off<<=1){
    int y = __shfl_up(x, off, 64);
    if ((t & 63) >= off) x += y;
  }
  if ((t & 63) == 63) wps[t >> 6] = x;
  __syncthreads();
  if (t < 4){
    int wv = wps[t];
    int wx = wv;
    #pragma unroll
    for (int off=1; off<4; off<<=1){
      int y = __shfl_up(wx, off, 4);
      if (t >= off) wx += y;
    }
    wps[t] = wx - wv;
  }
  __syncthreads();
  int sv = (x - v) + wps[t >> 6];   // exclusive prefix over dl
  start[t] = sv;
  int node = (b << BSH) + t;
  if (node <= NN) rowp[node] = base + sv;
  __syncthreads();
  for (int i=t; i<n; i+=256){
    unsigned r = bktData[base+i];
    int dl = (r >> 20) & 0xFF;
    int p = start[dl] + atomicAdd(&cnt[dl], 1);
    packed[base + p] = (int)r;      // keep src|rel|dl
  }
}

// Per-node per-relation gate partials + f16 tables:
// dA[n][r] (f32, dst side), dbrec[n][r] (f16, src side), xrec[n][0:32] (f16 features)
__global__ __launch_bounds__(256) void k_dots(const float* __restrict__ x, const float* __restrict__ wsum,
    float* __restrict__ dA, __half* __restrict__ dbrec, __half* __restrict__ xrec){
  __shared__ float wl[RR*DD];                  // wl[j*16+rel] = wsum[rel*64+j]
  for (int i = threadIdx.x; i < RR*DD; i += 256){
    int r = i & 15; int j = i >> 4;
    wl[i] = wsum[r*DD + j];
  }
  __syncthreads();
  int t = blockIdx.x*256 + threadIdx.x;
  if (t >= NN*RR) return;
  int n = t >> 4, r = t & 15;
  const float* xr = x + (size_t)n*ENCD;
  float a = 0.f, b = 0.f;
  float xlo = 0.f, xhi = 0.f;
  #pragma unroll
  for (int q=0;q<8;q++){
    float4 v = ld4(xr + 4*q);
    int j = 4*q;
    if (r >= j && r < j+4){ float tmp[4]={v.x,v.y,v.z,v.w}; xlo = tmp[r-j]; }
    if (r+16 >= j && r+16 < j+4){ float tmp[4]={v.x,v.y,v.z,v.w}; xhi = tmp[r+16-j]; }
    a = fmaf(v.x, wl[(j+0)*16 + r], a);
    a = fmaf(v.y, wl[(j+1)*16 + r], a);
    a = fmaf(v.z, wl[(j+2)*16 + r], a);
    a = fmaf(v.w, wl[(j+3)*16 + r], a);
    b = fmaf(v.x, wl[(32+j+0)*16 + r], b);
    b = fmaf(v.y, wl[(32+j+1)*16 + r], b);
    b = fmaf(v.z, wl[(32+j+2)*16 + r], b);
    b = fmaf(v.w, wl[(32+j+3)*16 + r], b);
  }
  dA[t] = a;
  dbrec[t] = __float2half(b);
  xrec[(size_t)n*32 + r]      = __float2half(xlo);
  xrec[(size_t)n*32 + 16 + r] = __float2half(xhi);
}

// Per-edge gate pass: sequential packed stream, L2-resident dbrec gather, f16 gate stream out
__global__ __launch_bounds__(256) void k_gates(const int* __restrict__ packed,
    const int* __restrict__ bktBase, const int* __restrict__ bktCnt,
    const float* __restrict__ dA, const __half* __restrict__ dbrec, __half* __restrict__ gat){
  int b = blockIdx.x >> 2, g = blockIdx.x & 3;
  int base = bktBase[b], n = bktCnt[b];
  int lo = (n*g) >> 2, hi = (n*(g+1)) >> 2;
  for (int i = lo + (int)threadIdx.x; i < hi; i += 256){
    int p = packed[base+i];
    int s = p & 0xFFFF;
    int r = (p >> 16) & 15;
    int dl = (p >> 20) & 0xFF;
    int dst = (b << BSH) | dl;
    float z = dA[dst*16 + r] + __half2float(dbrec[s*16 + r]);
    gat[base+i] = __float2half(1.f/(1.f + __expf(-z)));
  }
}

// Scatter-mean via CSR gather: 16 lanes per node, only xrec (L2-resident) gathered
__global__ __launch_bounds__(256) void k_agg(const __half2* __restrict__ xrec2, const int* __restrict__ packed,
    const __half* __restrict__ gat, const int* __restrict__ rowp, float* __restrict__ agg){
  int node = blockIdx.x*16 + (threadIdx.x >> 4);
  int l = threadIdx.x & 15;
  if (node >= NN) return;
  int beg = rowp[node], end = rowp[node+1];
  float ax = 0.f, ay = 0.f;
  #pragma unroll 4
  for (int i = beg; i < end; i++){
    int p = packed[i];
    int s = p & 0xFFFF;
    float g = __half2float(gat[i]);
    float2 fx = __half22float2(xrec2[(size_t)s*16 + l]);
    ax = fmaf(fx.x, g, ax);
    ay = fmaf(fx.y, g, ay);
  }
  int deg = end - beg;
  float inv = (deg > 0) ? 1.f/(float)deg : 0.f;
  float2 o; o.x = ax*inv; o.y = ay*inv;
  *reinterpret_cast<float2*>(&agg[(size_t)node*ENCD + 2*l]) = o;
}

// out = leaky_relu(concat(x,agg) @ W + b), W is [64][outd]
__global__ __launch_bounds__(256) void k_lin(const float* __restrict__ x, const float* __restrict__ agg,
    const float* __restrict__ W, const float* __restrict__ b, float* __restrict__ out, int outd){
  int n = blockIdx.x*256 + threadIdx.x;
  if (n >= NN) return;
  int k0 = blockIdx.y * 16;
  const float* xr = x   + (size_t)n*ENCD;
  const float* ar = agg + (size_t)n*ENCD;
  float xv[32], av[32];
  #pragma unroll
  for (int q=0;q<8;q++){ float4 v = ld4(xr+4*q); xv[4*q]=v.x; xv[4*q+1]=v.y; xv[4*q+2]=v.z; xv[4*q+3]=v.w; }
  #pragma unroll
  for (int q=0;q<8;q++){ float4 v = ld4(ar+4*q); av[4*q]=v.x; av[4*q+1]=v.y; av[4*q+2]=v.z; av[4*q+3]=v.w; }
  float acc[16];
  #pragma unroll
  for (int t=0;t<16;t++) acc[t] = b[k0+t];
  #pragma unroll
  for (int j=0;j<32;j++){
    #pragma unroll
    for (int t=0;t<16;t++) acc[t] = fmaf(xv[j], W[(size_t)j*outd + k0 + t], acc[t]);
  }
  #pragma unroll
  for (int j=0;j<32;j++){
    #pragma unroll
    for (int t=0;t<16;t++) acc[t] = fmaf(av[j], W[(size_t)(32+j)*outd + k0 + t], acc[t]);
  }
  float* o = out + (size_t)n*outd + k0;
  #pragma unroll
  for (int q=0;q<4;q++){
    float4 v;
    float a0=acc[4*q],a1=acc[4*q+1],a2=acc[4*q+2],a3=acc[4*q+3];
    v.x = a0>0.f? a0 : 0.01f*a0;
    v.y = a1>0.f? a1 : 0.01f*a1;
    v.z = a2>0.f? a2 : 0.01f*a2;
    v.w = a3>0.f? a3 : 0.01f*a3;
    st4(o + 4*q, v);
  }
}

__global__ __launch_bounds__(256) void k_score(const float* __restrict__ x1, const float* __restrict__ x2,
    const int* __restrict__ users, const int* __restrict__ items, float* __restrict__ out, int Bn){
  int b = blockIdx.x*256 + threadIdx.x;
  if (b >= Bn) return;
  int u  = N_ENT + users[b];
  int it = items[b];
  const float* a1 = x1 + (size_t)u*32;
  const float* c1 = x1 + (size_t)it*32;
  const float* a2 = x2 + (size_t)u*16;
  const float* c2 = x2 + (size_t)it*16;
  float s = 0.f;
  #pragma unroll
  for (int q=0;q<8;q++){
    float4 va=ld4(a1+4*q), vb=ld4(c1+4*q);
    s = fmaf(va.x,vb.x,s); s = fmaf(va.y,vb.y,s); s = fmaf(va.z,vb.z,s); s = fmaf(va.w,vb.w,s);
  }
  #pragma unroll
  for (int q=0;q<4;q++){
    float4 va=ld4(a2+4*q), vb=ld4(c2+4*q);
    s = fmaf(va.x,vb.x,s); s = fmaf(va.y,vb.y,s); s = fmaf(va.z,vb.z,s); s = fmaf(va.w,vb.w,s);
  }
  out[b] = s;
}

extern "C" void kernel_launch(void* const* d_in, const int* in_sizes, int n_in,
                              void* d_out, int out_size, void* d_ws, size_t ws_size,
                              hipStream_t stream){
  const int*   users   = (const int*)d_in[0];
  const int*   items   = (const int*)d_in[1];
  const int*   esrc    = (const int*)d_in[2];
  const int*   edst    = (const int*)d_in[3];
  const int*   erel    = (const int*)d_in[4];
  const float* ent     = (const float*)d_in[5];
  const float* usr     = (const float*)d_in[6];
  const float* enc_W0  = (const float*)d_in[7];
  const float* enc_b0  = (const float*)d_in[8];
  const float* enc_W1  = (const float*)d_in[9];
  const float* enc_b1  = (const float*)d_in[10];
  const float* dec_W0  = (const float*)d_in[11];
  const float* dec_b0  = (const float*)d_in[12];
  const float* dec_W1  = (const float*)d_in[13];
  const float* dec_b1  = (const float*)d_in[14];
  const float* Wr1     = (const float*)d_in[15];
  const float* lin_W1  = (const float*)d_in[16];
  const float* lin_b1  = (const float*)d_in[17];
  const float* Wr2     = (const float*)d_in[18];
  const float* lin_W2  = (const float*)d_in[19];
  const float* lin_b2  = (const float*)d_in[20];
  const int E = in_sizes[2];
  const int B = in_sizes[0];

  char* wp = (char*)d_ws;
  auto carve = [&](size_t bytes)->char*{ char* p = wp; wp += (bytes + 255) & ~(size_t)255; return p; };
  float* enc    = (float*)carve((size_t)NN*32*4);
  float* x1     = (float*)carve((size_t)NN*32*4);
  float* x2     = (float*)carve((size_t)NN*16*4);
  float* agg    = (float*)carve((size_t)NN*32*4);
  float* wsum   = (float*)carve((size_t)2*RR*DD*4);
  float* dA     = (float*)carve((size_t)NN*RR*4);
  __half* dbrec = (__half*)carve((size_t)NN*RR*2);   // 32B/node src-side gate dots
  __half* xrec  = (__half*)carve((size_t)NN*32*2);   // 64B/node f16 features
  __half* gat   = (__half*)carve((size_t)E*2);       // per-edge gate stream
  int*   packed = (int*)  carve((size_t)E*4);
  unsigned* bktData = (unsigned*)carve((size_t)E*4);
  int*   bktCnt = (int*)  carve((size_t)2*NB*4);     // cnt[256] + fill[256], one memset
  int*   bktFill= bktCnt + NB;
  int*   bktBase= (int*)  carve(NB*4);
  int*   rowp   = (int*)  carve(((size_t)NN+1)*4);

  const int nbN = (NN + 255)/256;   // 235
  const int nbT = (E + 4095)/4096;  // 4096-edge tiles
  const int nbD = (NN*RR + 255)/256;
  dim3 blk(256);

  hipMemsetAsync(d_out, 0, (size_t)out_size*sizeof(float), stream);
  hipMemsetAsync(bktCnt, 0, (size_t)2*NB*sizeof(int), stream);

  k_wsum <<<dim3((2*RR*DD+255)/256), blk, 0, stream>>>(Wr1, Wr2, wsum);
  k_ae   <<<dim3((NN+63)/64), blk, 0, stream>>>(ent, usr, enc_W0, enc_b0, enc_W1, enc_b1,
                                                dec_W0, dec_b0, dec_W1, dec_b1,
                                                enc, ((float*)d_out) + B);

  // CSR build via 256-bucket two-phase counting sort
  k_hist256<<<nbT, blk, 0, stream>>>(edst, bktCnt, E);
  k_scan256<<<1, blk, 0, stream>>>(bktCnt, bktBase);
  k_bucketA<<<nbT, blk, 0, stream>>>(esrc, edst, erel, bktBase, bktFill, bktData, E);
  k_buildB <<<NBU, blk, 0, stream>>>(bktData, bktBase, bktCnt, rowp, packed);

  k_dots <<<nbD, blk, 0, stream>>>(enc, wsum, dA, dbrec, xrec);
  k_gates<<<NBU*4, blk, 0, stream>>>(packed, bktBase, bktCnt, dA, dbrec, gat);
  k_agg  <<<(NN+15)/16, blk, 0, stream>>>((const __half2*)xrec, packed, gat, rowp, agg);
  k_lin  <<<dim3(nbN, 2), blk, 0, stream>>>(enc, agg, lin_W1, lin_b1, x1, 32);

  k_dots <<<nbD, blk, 0, stream>>>(x1, wsum + RR*DD, dA, dbrec, xrec);
  k_gates<<<NBU*4, blk, 0, stream>>>(packed, bktBase, bktCnt, dA, dbrec, gat);
  k_agg  <<<(NN+15)/16, blk, 0, stream>>>((const __half2*)xrec, packed, gat, rowp, agg);
  k_lin  <<<dim3(nbN, 1), blk, 0, stream>>>(x1, agg, lin_W2, lin_b2, x2, 16);

  k_score<<<(B+255)/256, blk, 0, stream>>>(x1, x2, users, items, (float*)d_out, B);
}

// Round 8
// 383.205 us; speedup vs baseline: 2.1086x; 1.0269x over previous
//
#include <hip/hip_runtime.h>
#include <hip/hip_fp16.h>
#include <math.h>

#define N_ENT 50000
#define N_USR 10000
#define NN    60000
#define DD    64
#define H0    128
#define ENCD  32
#define RR    16
#define NB    256
#define BSH   8
#define NBU   235   // ceil(NN/256): buckets actually used

__device__ __forceinline__ float4 ld4(const float* p){ return *reinterpret_cast<const float4*>(p); }
__device__ __forceinline__ void st4(float* p, float4 v){ *reinterpret_cast<float4*>(p) = v; }

// w_sum[layer][r*64+j] = sum_k Wr[r][j][k]
__global__ __launch_bounds__(256) void k_wsum(const float* __restrict__ Wr1, const float* __restrict__ Wr2,
                                              float* __restrict__ wsum){
  int i = blockIdx.x*256 + threadIdx.x;        // 0..2047
  if (i >= 2*RR*DD) return;
  const float* Wr = (i < RR*DD) ? Wr1 : Wr2;
  int loc = i & (RR*DD - 1);                   // r*64+j
  const float* p = Wr + (size_t)loc*32;
  float s = 0.f;
  #pragma unroll
  for (int k=0;k<32;k++) s += p[k];
  wsum[i] = s;
}

// Fully fused autoencoder: x -> h1 -> enc -> h2 -> dec -> loss, one block = 64 nodes.
// 512 threads (8 waves) over the same 58KB LDS: 2 blocks/CU -> 16 waves/CU (4/SIMD).
// LDS tiles stored [feature][node] stride 65; per-wave output tiles are wave-uniform.
__global__ __launch_bounds__(512) void k_ae(const float* __restrict__ ent, const float* __restrict__ usr,
    const float* __restrict__ eW0, const float* __restrict__ eb0,
    const float* __restrict__ eW1, const float* __restrict__ eb1,
    const float* __restrict__ dW0c, const float* __restrict__ db0,
    const float* __restrict__ dW1c, const float* __restrict__ db1,
    float* __restrict__ enc, float* __restrict__ loss_out){
  __shared__ float xs[DD][65];     // 16.6 KB
  __shared__ float hs[H0][65];     // 33.3 KB  (h1, then h2)
  __shared__ float es[ENCD][65];   // 8.3 KB
  __shared__ float sred[8];
  int t = threadIdx.x;
  int nl = t & 63;
  int wid = __builtin_amdgcn_readfirstlane(t >> 6);   // wave-uniform 0..7

  // stage x: thread t loads 8 floats of node (t>>3), cols (t&7)*8..+7, transposed into xs
  {
    int n2 = t >> 3;
    int d0 = (t & 7) * 8;
    int gnode = blockIdx.x*64 + n2;
    if (gnode < NN){
      const float* xr = (gnode < N_ENT) ? ent + (size_t)gnode*DD : usr + (size_t)(gnode-N_ENT)*DD;
      #pragma unroll
      for (int q=0;q<2;q++){
        float4 v = ld4(xr + d0 + 4*q);
        xs[d0+4*q+0][n2]=v.x; xs[d0+4*q+1][n2]=v.y; xs[d0+4*q+2][n2]=v.z; xs[d0+4*q+3][n2]=v.w;
      }
    } else {
      #pragma unroll
      for (int q=0;q<8;q++) xs[d0+q][n2]=0.f;
    }
  }
  __syncthreads();

  // phase1: h1[j0..j0+15] = relu(x @ eW0 + eb0)
  {
    int j0 = wid*16;
    float acc[16];
    #pragma unroll
    for (int k=0;k<16;k++) acc[k]=eb0[j0+k];
    #pragma unroll 4
    for (int d=0;d<DD;d++){
      float x = xs[d][nl];
      const float* w = eW0 + (size_t)d*H0 + j0;
      #pragma unroll
      for (int k=0;k<16;k++) acc[k]=fmaf(x,w[k],acc[k]);
    }
    #pragma unroll
    for (int k=0;k<16;k++) hs[j0+k][nl]=fmaxf(acc[k],0.f);
  }
  __syncthreads();

  // phase2: enc[k0..k0+3] = h1 @ eW1 + eb1
  {
    int k0 = wid*4;
    float acc[4];
    #pragma unroll
    for (int k=0;k<4;k++) acc[k]=eb1[k0+k];
    #pragma unroll 4
    for (int j=0;j<H0;j++){
      float hv = hs[j][nl];
      const float* w = eW1 + (size_t)j*ENCD + k0;
      #pragma unroll
      for (int k=0;k<4;k++) acc[k]=fmaf(hv,w[k],acc[k]);
    }
    #pragma unroll
    for (int k=0;k<4;k++) es[k0+k][nl]=acc[k];
  }
  __syncthreads();

  // coalesced enc writeout: thread t stores 16B of node (t>>3)
  {
    int n2 = t >> 3;
    int k2 = (t & 7) * 4;
    int gnode = blockIdx.x*64 + n2;
    if (gnode < NN){
      float4 a;
      a.x=es[k2+0][n2]; a.y=es[k2+1][n2]; a.z=es[k2+2][n2]; a.w=es[k2+3][n2];
      st4(enc + (size_t)gnode*ENCD + k2, a);
    }
  }

  // phase3: h2[j0..j0+15] = relu(enc @ dW0 + db0)  (reads es, overwrites hs — post-sync safe)
  {
    int j0 = wid*16;
    float acc[16];
    #pragma unroll
    for (int k=0;k<16;k++) acc[k]=db0[j0+k];
    #pragma unroll 4
    for (int d=0;d<ENCD;d++){
      float x = es[d][nl];
      const float* w = dW0c + (size_t)d*H0 + j0;
      #pragma unroll
      for (int k=0;k<16;k++) acc[k]=fmaf(x,w[k],acc[k]);
    }
    #pragma unroll
    for (int k=0;k<16;k++) hs[j0+k][nl]=fmaxf(acc[k],0.f);
  }
  __syncthreads();

  // phase4: dec[c0..c0+7] = h2 @ dW1 + db1 ; accumulate (dec-x)^2
  float part = 0.f;
  {
    int c0 = wid*8;
    float acc[8];
    #pragma unroll
    for (int k=0;k<8;k++) acc[k]=db1[c0+k];
    #pragma unroll 4
    for (int j=0;j<H0;j++){
      float hv = hs[j][nl];
      const float* w = dW1c + (size_t)j*DD + c0;
      #pragma unroll
      for (int k=0;k<8;k++) acc[k]=fmaf(hv,w[k],acc[k]);
    }
    int gnode = blockIdx.x*64 + nl;
    if (gnode < NN){
      #pragma unroll
      for (int k=0;k<8;k++){ float d_ = acc[k]-xs[c0+k][nl]; part = fmaf(d_,d_,part); }
    }
  }
  #pragma unroll
  for (int off=32; off>0; off>>=1) part += __shfl_down(part, off, 64);
  if ((t&63)==0) sred[wid] = part;
  __syncthreads();
  if (t==0){
    float s = 0.f;
    #pragma unroll
    for (int k=0;k<8;k++) s += sred[k];
    atomicAdd(loss_out, s * (1.0f/((float)NN*(float)DD)));
  }
}

// 256-bucket histogram of edge destinations
__global__ __launch_bounds__(256) void k_hist256(const int* __restrict__ edst, int* __restrict__ bktCnt, int E_){
  __shared__ int h[NB];
  h[threadIdx.x]=0;
  __syncthreads();
  int i0 = blockIdx.x*4096;
  #pragma unroll
  for (int k=0;k<16;k++){
    int e = i0 + k*256 + threadIdx.x;
    if (e < E_) atomicAdd(&h[((unsigned)edst[e])>>BSH], 1);
  }
  __syncthreads();
  int c = h[threadIdx.x];
  if (c) atomicAdd(&bktCnt[threadIdx.x], c);
}

// exclusive scan of 256 bucket counts (one block)
__global__ __launch_bounds__(256) void k_scan256(const int* __restrict__ bktCnt, int* __restrict__ bktBase){
  __shared__ int wps[4];
  int t = threadIdx.x;
  int v = bktCnt[t];
  int x = v;
  #pragma unroll
  for (int off=1; off<64; off<<=1){
    int y = __shfl_up(x, off, 64);
    if ((t & 63) >= off) x += y;
  }
  if ((t & 63) == 63) wps[t >> 6] = x;
  __syncthreads();
  if (t < 4){
    int wv = wps[t];
    int wx = wv;
    #pragma unroll
    for (int off=1; off<4; off<<=1){
      int y = __shfl_up(wx, off, 4);
      if (t >= off) wx += y;
    }
    wps[t] = wx - wv;
  }
  __syncthreads();
  bktBase[t] = (x - v) + wps[t >> 6];
}

// bucketed append: each block reserves exclusive contiguous chunks per bucket
__global__ __launch_bounds__(256) void k_bucketA(const int* __restrict__ esrc, const int* __restrict__ edst,
    const int* __restrict__ erel, const int* __restrict__ bktBase, int* __restrict__ bktFill,
    unsigned* __restrict__ bktData, int E_){
  __shared__ int h[NB];
  __shared__ int gbase[NB];
  h[threadIdx.x]=0;
  __syncthreads();
  int i0 = blockIdx.x*4096;
  int dcache[16];
  #pragma unroll
  for (int k=0;k<16;k++){
    int e = i0 + k*256 + threadIdx.x;
    int d = (e < E_) ? edst[e] : -1;
    dcache[k] = d;
    if (d >= 0) atomicAdd(&h[((unsigned)d)>>BSH], 1);
  }
  __syncthreads();
  {
    int c = h[threadIdx.x];
    int off = c ? atomicAdd(&bktFill[threadIdx.x], c) : 0;
    gbase[threadIdx.x] = bktBase[threadIdx.x] + off;
    h[threadIdx.x] = 0;   // reuse as local fill
  }
  __syncthreads();
  #pragma unroll
  for (int k=0;k<16;k++){
    int e = i0 + k*256 + threadIdx.x;
    if (e >= E_) continue;
    int d = dcache[k];
    int b = ((unsigned)d) >> BSH;
    int slot = atomicAdd(&h[b], 1);
    unsigned rec = (unsigned)esrc[e] | ((unsigned)erel[e] << 16) | ((unsigned)(d & 0xFF) << 20);
    bktData[(size_t)gbase[b] + slot] = rec;
  }
}

// per-bucket CSR build: counts+scan in LDS, localized writes; keeps dl bits in packed
__global__ __launch_bounds__(256) void k_buildB(const unsigned* __restrict__ bktData,
    const int* __restrict__ bktBase, const int* __restrict__ bktCnt,
    int* __restrict__ rowp, int* __restrict__ packed){
  __shared__ int cnt[NB];
  __shared__ int start[NB];
  __shared__ int wps[4];
  int b = blockIdx.x;
  int base = bktBase[b];
  int n = bktCnt[b];
  int t = threadIdx.x;
  cnt[t] = 0;
  __syncthreads();
  for (int i=t; i<n; i+=256) atomicAdd(&cnt[(bktData[base+i] >> 20) & 0xFF], 1);
  __syncthreads();
  int v = cnt[t];
  cnt[t] = 0;                       // reset for fill pass
  int x = v;
  #pragma unroll
  for (int off=1; off<64; off<<=1){
    int y = __shfl_up(x, off, 64);
    if ((t & 63) >= off) x += y;
  }
  if ((t & 63) == 63) wps[t >> 6] = x;
  __syncthreads();
  if (t < 4){
    int wv = wps[t];
    int wx = wv;
    #pragma unroll
    for (int off=1; off<4; off<<=1){
      int y = __shfl_up(wx, off, 4);
      if (t >= off) wx += y;
    }
    wps[t] = wx - wv;
  }
  __syncthreads();
  int sv = (x - v) + wps[t >> 6];   // exclusive prefix over dl
  start[t] = sv;
  int node = (b << BSH) + t;
  if (node <= NN) rowp[node] = base + sv;
  __syncthreads();
  for (int i=t; i<n; i+=256){
    unsigned r = bktData[base+i];
    int dl = (r >> 20) & 0xFF;
    int p = start[dl] + atomicAdd(&cnt[dl], 1);
    packed[base + p] = (int)r;      // keep src|rel|dl
  }
}

// Per-node per-relation gate partials + f16 tables:
// dA[n][r] (f32, dst side), dbrec[n][r] (f16, src side), xrec[n][0:32] (f16 features)
__global__ __launch_bounds__(256) void k_dots(const float* __restrict__ x, const float* __restrict__ wsum,
    float* __restrict__ dA, __half* __restrict__ dbrec, __half* __restrict__ xrec){
  __shared__ float wl[RR*DD];                  // wl[j*16+rel] = wsum[rel*64+j]
  for (int i = threadIdx.x; i < RR*DD; i += 256){
    int r = i & 15; int j = i >> 4;
    wl[i] = wsum[r*DD + j];
  }
  __syncthreads();
  int t = blockIdx.x*256 + threadIdx.x;
  if (t >= NN*RR) return;
  int n = t >> 4, r = t & 15;
  const float* xr = x + (size_t)n*ENCD;
  float a = 0.f, b = 0.f;
  float xlo = 0.f, xhi = 0.f;
  #pragma unroll
  for (int q=0;q<8;q++){
    float4 v = ld4(xr + 4*q);
    int j = 4*q;
    if (r >= j && r < j+4){ float tmp[4]={v.x,v.y,v.z,v.w}; xlo = tmp[r-j]; }
    if (r+16 >= j && r+16 < j+4){ float tmp[4]={v.x,v.y,v.z,v.w}; xhi = tmp[r+16-j]; }
    a = fmaf(v.x, wl[(j+0)*16 + r], a);
    a = fmaf(v.y, wl[(j+1)*16 + r], a);
    a = fmaf(v.z, wl[(j+2)*16 + r], a);
    a = fmaf(v.w, wl[(j+3)*16 + r], a);
    b = fmaf(v.x, wl[(32+j+0)*16 + r], b);
    b = fmaf(v.y, wl[(32+j+1)*16 + r], b);
    b = fmaf(v.z, wl[(32+j+2)*16 + r], b);
    b = fmaf(v.w, wl[(32+j+3)*16 + r], b);
  }
  dA[t] = a;
  dbrec[t] = __float2half(b);
  xrec[(size_t)n*32 + r]      = __float2half(xlo);
  xrec[(size_t)n*32 + 16 + r] = __float2half(xhi);
}

// Per-edge gate pass: sequential packed stream, L2-resident dbrec gather, f16 gate stream out
__global__ __launch_bounds__(256) void k_gates(const int* __restrict__ packed,
    const int* __restrict__ bktBase, const int* __restrict__ bktCnt,
    const float* __restrict__ dA, const __half* __restrict__ dbrec, __half* __restrict__ gat){
  int b = blockIdx.x >> 2, g = blockIdx.x & 3;
  int base = bktBase[b], n = bktCnt[b];
  int lo = (n*g) >> 2, hi = (n*(g+1)) >> 2;
  for (int i = lo + (int)threadIdx.x; i < hi; i += 256){
    int p = packed[base+i];
    int s = p & 0xFFFF;
    int r = (p >> 16) & 15;
    int dl = (p >> 20) & 0xFF;
    int dst = (b << BSH) | dl;
    float z = dA[dst*16 + r] + __half2float(dbrec[s*16 + r]);
    gat[base+i] = __float2half(1.f/(1.f + __expf(-z)));
  }
}

// Scatter-mean via CSR gather: 16 lanes per node, only xrec (L2-resident) gathered
__global__ __launch_bounds__(256) void k_agg(const __half2* __restrict__ xrec2, const int* __restrict__ packed,
    const __half* __restrict__ gat, const int* __restrict__ rowp, float* __restrict__ agg){
  int node = blockIdx.x*16 + (threadIdx.x >> 4);
  int l = threadIdx.x & 15;
  if (node >= NN) return;
  int beg = rowp[node], end = rowp[node+1];
  float ax = 0.f, ay = 0.f;
  #pragma unroll 4
  for (int i = beg; i < end; i++){
    int p = packed[i];
    int s = p & 0xFFFF;
    float g = __half2float(gat[i]);
    float2 fx = __half22float2(xrec2[(size_t)s*16 + l]);
    ax = fmaf(fx.x, g, ax);
    ay = fmaf(fx.y, g, ay);
  }
  int deg = end - beg;
  float inv = (deg > 0) ? 1.f/(float)deg : 0.f;
  float2 o; o.x = ax*inv; o.y = ay*inv;
  *reinterpret_cast<float2*>(&agg[(size_t)node*ENCD + 2*l]) = o;
}

// out = leaky_relu(concat(x,agg) @ W + b), W is [64][outd]
__global__ __launch_bounds__(256) void k_lin(const float* __restrict__ x, const float* __restrict__ agg,
    const float* __restrict__ W, const float* __restrict__ b, float* __restrict__ out, int outd){
  int n = blockIdx.x*256 + threadIdx.x;
  if (n >= NN) return;
  int k0 = blockIdx.y * 16;
  const float* xr = x   + (size_t)n*ENCD;
  const float* ar = agg + (size_t)n*ENCD;
  float xv[32], av[32];
  #pragma unroll
  for (int q=0;q<8;q++){ float4 v = ld4(xr+4*q); xv[4*q]=v.x; xv[4*q+1]=v.y; xv[4*q+2]=v.z; xv[4*q+3]=v.w; }
  #pragma unroll
  for (int q=0;q<8;q++){ float4 v = ld4(ar+4*q); av[4*q]=v.x; av[4*q+1]=v.y; av[4*q+2]=v.z; av[4*q+3]=v.w; }
  float acc[16];
  #pragma unroll
  for (int t=0;t<16;t++) acc[t] = b[k0+t];
  #pragma unroll
  for (int j=0;j<32;j++){
    #pragma unroll
    for (int t=0;t<16;t++) acc[t] = fmaf(xv[j], W[(size_t)j*outd + k0 + t], acc[t]);
  }
  #pragma unroll
  for (int j=0;j<32;j++){
    #pragma unroll
    for (int t=0;t<16;t++) acc[t] = fmaf(av[j], W[(size_t)(32+j)*outd + k0 + t], acc[t]);
  }
  float* o = out + (size_t)n*outd + k0;
  #pragma unroll
  for (int q=0;q<4;q++){
    float4 v;
    float a0=acc[4*q],a1=acc[4*q+1],a2=acc[4*q+2],a3=acc[4*q+3];
    v.x = a0>0.f? a0 : 0.01f*a0;
    v.y = a1>0.f? a1 : 0.01f*a1;
    v.z = a2>0.f? a2 : 0.01f*a2;
    v.w = a3>0.f? a3 : 0.01f*a3;
    st4(o + 4*q, v);
  }
}

__global__ __launch_bounds__(256) void k_score(const float* __restrict__ x1, const float* __restrict__ x2,
    const int* __restrict__ users, const int* __restrict__ items, float* __restrict__ out, int Bn){
  int b = blockIdx.x*256 + threadIdx.x;
  if (b >= Bn) return;
  int u  = N_ENT + users[b];
  int it = items[b];
  const float* a1 = x1 + (size_t)u*32;
  const float* c1 = x1 + (size_t)it*32;
  const float* a2 = x2 + (size_t)u*16;
  const float* c2 = x2 + (size_t)it*16;
  float s = 0.f;
  #pragma unroll
  for (int q=0;q<8;q++){
    float4 va=ld4(a1+4*q), vb=ld4(c1+4*q);
    s = fmaf(va.x,vb.x,s); s = fmaf(va.y,vb.y,s); s = fmaf(va.z,vb.z,s); s = fmaf(va.w,vb.w,s);
  }
  #pragma unroll
  for (int q=0;q<4;q++){
    float4 va=ld4(a2+4*q), vb=ld4(c2+4*q);
    s = fmaf(va.x,vb.x,s); s = fmaf(va.y,vb.y,s); s = fmaf(va.z,vb.z,s); s = fmaf(va.w,vb.w,s);
  }
  out[b] = s;
}

extern "C" void kernel_launch(void* const* d_in, const int* in_sizes, int n_in,
                              void* d_out, int out_size, void* d_ws, size_t ws_size,
                              hipStream_t stream){
  const int*   users   = (const int*)d_in[0];
  const int*   items   = (const int*)d_in[1];
  const int*   esrc    = (const int*)d_in[2];
  const int*   edst    = (const int*)d_in[3];
  const int*   erel    = (const int*)d_in[4];
  const float* ent     = (const float*)d_in[5];
  const float* usr     = (const float*)d_in[6];
  const float* enc_W0  = (const float*)d_in[7];
  const float* enc_b0  = (const float*)d_in[8];
  const float* enc_W1  = (const float*)d_in[9];
  const float* enc_b1  = (const float*)d_in[10];
  const float* dec_W0  = (const float*)d_in[11];
  const float* dec_b0  = (const float*)d_in[12];
  const float* dec_W1  = (const float*)d_in[13];
  const float* dec_b1  = (const float*)d_in[14];
  const float* Wr1     = (const float*)d_in[15];
  const float* lin_W1  = (const float*)d_in[16];
  const float* lin_b1  = (const float*)d_in[17];
  const float* Wr2     = (const float*)d_in[18];
  const float* lin_W2  = (const float*)d_in[19];
  const float* lin_b2  = (const float*)d_in[20];
  const int E = in_sizes[2];
  const int B = in_sizes[0];

  char* wp = (char*)d_ws;
  auto carve = [&](size_t bytes)->char*{ char* p = wp; wp += (bytes + 255) & ~(size_t)255; return p; };
  float* enc    = (float*)carve((size_t)NN*32*4);
  float* x1     = (float*)carve((size_t)NN*32*4);
  float* x2     = (float*)carve((size_t)NN*16*4);
  float* agg    = (float*)carve((size_t)NN*32*4);
  float* wsum   = (float*)carve((size_t)2*RR*DD*4);
  float* dA     = (float*)carve((size_t)NN*RR*4);
  __half* dbrec = (__half*)carve((size_t)NN*RR*2);   // 32B/node src-side gate dots
  __half* xrec  = (__half*)carve((size_t)NN*32*2);   // 64B/node f16 features
  __half* gat   = (__half*)carve((size_t)E*2);       // per-edge gate stream
  int*   packed = (int*)  carve((size_t)E*4);
  unsigned* bktData = (unsigned*)carve((size_t)E*4);
  int*   bktCnt = (int*)  carve((size_t)2*NB*4);     // cnt[256] + fill[256], one memset
  int*   bktFill= bktCnt + NB;
  int*   bktBase= (int*)  carve(NB*4);
  int*   rowp   = (int*)  carve(((size_t)NN+1)*4);

  const int nbN = (NN + 255)/256;   // 235
  const int nbT = (E + 4095)/4096;  // 4096-edge tiles
  const int nbD = (NN*RR + 255)/256;
  dim3 blk(256);

  hipMemsetAsync(d_out, 0, (size_t)out_size*sizeof(float), stream);
  hipMemsetAsync(bktCnt, 0, (size_t)2*NB*sizeof(int), stream);

  k_wsum <<<dim3((2*RR*DD+255)/256), blk, 0, stream>>>(Wr1, Wr2, wsum);
  k_ae   <<<dim3((NN+63)/64), dim3(512), 0, stream>>>(ent, usr, enc_W0, enc_b0, enc_W1, enc_b1,
                                                      dec_W0, dec_b0, dec_W1, dec_b1,
                                                      enc, ((float*)d_out) + B);

  // CSR build via 256-bucket two-phase counting sort
  k_hist256<<<nbT, blk, 0, stream>>>(edst, bktCnt, E);
  k_scan256<<<1, blk, 0, stream>>>(bktCnt, bktBase);
  k_bucketA<<<nbT, blk, 0, stream>>>(esrc, edst, erel, bktBase, bktFill, bktData, E);
  k_buildB <<<NBU, blk, 0, stream>>>(bktData, bktBase, bktCnt, rowp, packed);

  k_dots <<<nbD, blk, 0, stream>>>(enc, wsum, dA, dbrec, xrec);
  k_gates<<<NBU*4, blk, 0, stream>>>(packed, bktBase, bktCnt, dA, dbrec, gat);
  k_agg  <<<(NN+15)/16, blk, 0, stream>>>((const __half2*)xrec, packed, gat, rowp, agg);
  k_lin  <<<dim3(nbN, 2), blk, 0, stream>>>(enc, agg, lin_W1, lin_b1, x1, 32);

  k_dots <<<nbD, blk, 0, stream>>>(x1, wsum + RR*DD, dA, dbrec, xrec);
  k_gates<<<NBU*4, blk, 0, stream>>>(packed, bktBase, bktCnt, dA, dbrec, gat);
  k_agg  <<<(NN+15)/16, blk, 0, stream>>>((const __half2*)xrec, packed, gat, rowp, agg);
  k_lin  <<<dim3(nbN, 1), blk, 0, stream>>>(x1, agg, lin_W2, lin_b2, x2, 16);

  k_score<<<(B+255)/256, blk, 0, stream>>>(x1, x2, users, items, (float*)d_out, B);
}